// Round 13
// baseline (930.837 us; speedup 1.0000x reference)
//
#include <hip/hip_runtime.h>
#include <stddef.h>

// Problem constants (E=2 experts, NB=2 blocks, B=8 batch, N=512 nodes)
#define EE 2
#define NBK 2
#define BATCH 8

typedef unsigned short ushort_t;
typedef short bf16x8 __attribute__((ext_vector_type(8)));
typedef float f32x4 __attribute__((ext_vector_type(4)));
typedef unsigned short u16x4 __attribute__((ext_vector_type(4)));

__device__ __forceinline__ ushort_t f2bf(float f) {
    unsigned int u = __float_as_uint(f);
    u += 0x7FFF + ((u >> 16) & 1);
    return (ushort_t)(u >> 16);
}
__device__ __forceinline__ float bf2f(ushort_t h) {
    return __uint_as_float(((unsigned int)h) << 16);
}

// ---------------------------------------------------------------------------
__global__ __launch_bounds__(256) void k_rowsum(const float* __restrict__ adj,
                                                float* __restrict__ di) {
    int v = blockIdx.x;
    int tid = threadIdx.x;
    float s = 0.f;
    for (int w = tid; w < 512; w += 256)
        s += adj[v * 512 + w] + (w == v ? 1.f : 0.f);
    for (int off = 32; off; off >>= 1) s += __shfl_down(s, off);
    __shared__ float red[4];
    if ((tid & 63) == 0) red[tid >> 6] = s;
    __syncthreads();
    if (tid == 0) {
        float t = red[0] + red[1] + red[2] + red[3];
        di[v] = rsqrtf(t);
    }
}

// Packed B' layout: Bp[v][2048], segments k: [0,512)=An, [512,1024)=An2,
// [1024,1536)=AnT, [1536,2048)=An2T.  Bp[v][k] = B_seg[v][w].
__global__ __launch_bounds__(256) void k_norm(const float* __restrict__ adj,
                                              const float* __restrict__ di,
                                              ushort_t* __restrict__ Bp) {
    int idx = blockIdx.x * 256 + threadIdx.x;  // 0..262143
    int v = idx >> 9, w = idx & 511;
    float a = adj[idx] + (v == w ? 1.f : 0.f);
    ushort_t val = f2bf(di[v] * a * di[w]);
    Bp[(size_t)v * 2048 + w] = val;             // An
    Bp[(size_t)w * 2048 + 1024 + v] = val;      // AnT
}

// ---------------------------------------------------------------------------
// An2 = An·An; An2T = An2^T; written into Bp segments 1 and 3.
__global__ __launch_bounds__(256) void k_An2(ushort_t* __restrict__ Bp) {
    int tid = threadIdx.x;
    int w = tid >> 6, lane = tid & 63;
    int l15 = lane & 15, lg = lane >> 4;
    int wbase = blockIdx.x * 256 + w * 64;
    int n0 = blockIdx.y * 64;
    f32x4 acc[4][4] = {};
    const ushort_t* Ap = Bp + (size_t)(wbase + l15) * 2048 + lg * 8;          // An
    const ushort_t* Bo = Bp + (size_t)(n0 + l15) * 2048 + 1024 + lg * 8;      // AnT
    bf16x8 avC[4], bvC[4], avN[4], bvN[4];
#pragma unroll
    for (int i = 0; i < 4; ++i) {
        avC[i] = *(const bf16x8*)(Ap + (size_t)i * 16 * 2048);
        bvC[i] = *(const bf16x8*)(Bo + (size_t)i * 16 * 2048);
    }
#pragma unroll 2
    for (int k0 = 0; k0 < 512; k0 += 32) {
        int kn = k0 + 32;
        if (kn < 512) {
#pragma unroll
            for (int i = 0; i < 4; ++i) {
                avN[i] = *(const bf16x8*)(Ap + (size_t)i * 16 * 2048 + kn);
                bvN[i] = *(const bf16x8*)(Bo + (size_t)i * 16 * 2048 + kn);
            }
        }
#pragma unroll
        for (int mf = 0; mf < 4; ++mf)
#pragma unroll
            for (int nf = 0; nf < 4; ++nf)
                acc[mf][nf] = __builtin_amdgcn_mfma_f32_16x16x32_bf16(
                    avC[mf], bvC[nf], acc[mf][nf], 0, 0, 0);
#pragma unroll
        for (int i = 0; i < 4; ++i) { avC[i] = avN[i]; bvC[i] = bvN[i]; }
    }
#pragma unroll
    for (int mf = 0; mf < 4; ++mf)
#pragma unroll
        for (int nf = 0; nf < 4; ++nf) {
            int col = n0 + 16 * nf + l15;
            int row0 = wbase + 16 * mf + 4 * lg;
            u16x4 q;
#pragma unroll
            for (int r = 0; r < 4; ++r) {
                ushort_t vb = f2bf(acc[mf][nf][r]);
                q[r] = vb;
                Bp[(size_t)(row0 + r) * 2048 + 512 + col] = vb;   // An2
            }
            *(u16x4*)(Bp + (size_t)col * 2048 + 1536 + row0) = q; // An2T
        }
}

// ---------------------------------------------------------------------------
// Fused per-kb weight prep (unchanged from round 12)
__global__ __launch_bounds__(256) void k_prep(
    const float* __restrict__ Wf2, const float* __restrict__ Wf3,
    const float* __restrict__ Wf5, const float* __restrict__ Wf7,
    const float* __restrict__ Wg2, const float* __restrict__ Wg3,
    const float* __restrict__ Wg5, const float* __restrict__ Wg7,
    ushort_t* __restrict__ Wb,
    const float* __restrict__ Wgc1, const float* __restrict__ bgc1,
    const float* __restrict__ Wgc2, const float* __restrict__ bgc2,
    ushort_t* __restrict__ Amix, float* __restrict__ bsum,
    const float* __restrict__ Wb1, const float* __restrict__ Wb2,
    const float* __restrict__ Wfc1, const float* __restrict__ Wfc2,
    ushort_t* __restrict__ Whd, float* __restrict__ rS, int kb) {
    int bx = blockIdx.x;
    if (bx < 112) {
        int idx = bx * 256 + threadIdx.x;  // 28672 total
        if (idx >= 2 * 2 * 7 * 2 * 16 * 32) return;
        int c = idx & 31;
        int t1 = idx >> 5;
        int o16 = t1 & 15;
        int t2 = t1 >> 4;
        int ot = t2 & 1;
        int t3 = t2 >> 1;
        int dt = t3 % 7;
        int t4 = t3 / 7;
        int fg = t4 & 1;
        int e = t4 >> 1;
        int ek = e * NBK + kb;
        int o = ot * 16 + o16;
        int grp = o >> 3, oo = o & 7;
        const int kstab[4] = {2, 3, 5, 7};
        int ks = kstab[grp];
        int lo = 7 - ks;
        float val = 0.f;
        if (dt >= lo) {
            int di = dt - lo;
            const float* W;
            if (grp == 0) W = (fg ? Wg2 : Wf2) + (size_t)ek * 512 + oo * 64 + c * 2 + di;
            else if (grp == 1) W = (fg ? Wg3 : Wf3) + (size_t)ek * 768 + oo * 96 + c * 3 + di;
            else if (grp == 2) W = (fg ? Wg5 : Wf5) + (size_t)ek * 1280 + oo * 160 + c * 5 + di;
            else W = (fg ? Wg7 : Wf7) + (size_t)ek * 1792 + oo * 224 + c * 7 + di;
            val = *W;
        }
        Wb[idx] = f2bf(val);
    } else if (bx < 114) {
        int e = bx - 112;
        int ek = e * NBK + kb;
        const float* W1 = Wgc1 + (size_t)ek * 32 * 96;
        const float* W2 = Wgc2 + (size_t)ek * 32 * 96;
        for (int idx = threadIdx.x; idx < 32 * 160; idx += 256) {
            int co = idx / 160, k = idx % 160;
            int slot = k >> 5, cp = k & 31;
            float val;
            if (slot == 0)
                val = W1[co * 96 + cp] + W1[co * 96 + 32 + cp] + W1[co * 96 + 64 + cp] +
                      W2[co * 96 + cp] + W2[co * 96 + 32 + cp] + W2[co * 96 + 64 + cp];
            else if (slot == 1) val = 0.5f * W1[co * 96 + 32 + cp] + W1[co * 96 + 64 + cp];
            else if (slot == 2) val = 0.25f * W1[co * 96 + 64 + cp];
            else if (slot == 3) val = 0.5f * W2[co * 96 + 32 + cp] + W2[co * 96 + 64 + cp];
            else val = 0.25f * W2[co * 96 + 64 + cp];
            Amix[((size_t)e * 32 + co) * 160 + k] = f2bf(val);
        }
        if (threadIdx.x < 32)
            bsum[e * 32 + threadIdx.x] =
                bgc1[ek * 32 + threadIdx.x] + bgc2[ek * 32 + threadIdx.x];
    } else {
        int e = bx - 114;
        int ek = e * NBK + kb;
        ushort_t* Wh = Whd + (size_t)e * 6144;
        for (int i = threadIdx.x; i < 2048; i += 256)
            Wh[i] = f2bf(Wb1[(size_t)ek * 2048 + i]);
        for (int i = threadIdx.x; i < 1024; i += 256) {
            int r = i >> 6, d = i & 63;
            Wh[2048 + i] = f2bf(r < 12 ? Wb2[(size_t)ek * 768 + r * 64 + d] : 0.f);
        }
        for (int i = threadIdx.x; i < 2048; i += 256)
            Wh[3072 + i] = f2bf(Wfc1[(size_t)ek * 2048 + i]);
        for (int i = threadIdx.x; i < 1024; i += 256) {
            int r = i >> 6, d = i & 63;
            Wh[5120 + i] = f2bf(r < 12 ? Wfc2[(size_t)ek * 768 + r * 64 + d] : 0.f);
        }
        if (threadIdx.x < 64) {
            int d = threadIdx.x;
            float s1 = 0.f, s2 = 0.f;
            for (int c = 0; c < 32; ++c) {
                s1 += Wb1[(size_t)ek * 2048 + d * 32 + c];
                s2 += Wfc1[(size_t)ek * 2048 + d * 32 + c];
            }
            rS[e * 128 + d] = s1;
            rS[e * 128 + 64 + d] = s2;
        }
    }
}

// ---------------------------------------------------------------------------
// start: writes x fp32 [eb][t][c][n] and bf16 mirror xb [eb][t][n][c]
__global__ __launch_bounds__(256) void k_start(const float* __restrict__ bkc,
                                               float* __restrict__ x,
                                               ushort_t* __restrict__ xb,
                                               const float* __restrict__ Wst,
                                               const float* __restrict__ bst,
                                               int kb) {
    int n = blockIdx.x * 256 + threadIdx.x;
    int t = blockIdx.y;
    int eb = blockIdx.z;
    int e = eb >> 3;
    int ek = e * NBK + kb;
    const float* Wp = Wst + (size_t)ek * 32 * 2;
    const float* bp = bst + (size_t)ek * 32;
    float in0 = 0.f, in1 = 0.f;
    if (t >= 14) {
        const float* p = bkc + ((size_t)(eb * 12 + (t - 14)) * 512 + n) * 2;
        in0 = p[0];
        in1 = p[1];
    }
    float* xo = x + ((size_t)(eb * 26 + t) * 32) * 512 + n;
    ushort_t tmp[32];
#pragma unroll
    for (int c = 0; c < 32; ++c) {
        float v = bp[c] + Wp[c * 2] * in0 + Wp[c * 2 + 1] * in1;
        xo[(size_t)c * 512] = v;
        tmp[c] = f2bf(v);
    }
    ushort_t* xbp = xb + ((size_t)(eb * 26 + t) * 512 + n) * 32;
#pragma unroll
    for (int q = 0; q < 4; ++q)
        *(bf16x8*)(xbp + q * 8) = *(bf16x8*)(tmp + q * 8);
}

// ---------------------------------------------------------------------------
// Fused inception + channel-mix: computes h tile [32 c][128 n] into LDS
// (transposed ht[n][c]), then As = M_s @ h for s=0..4:
//   s=0 -> g0 fp32 [ebj][32][512];  s=1..4 -> A' bf16 [ebj][32 co][2048 k],
//   k = (s-1)*512 + node.
__global__ __launch_bounds__(256) void k_incept2(
    const ushort_t* __restrict__ xb, ushort_t* __restrict__ Aprime,
    float* __restrict__ g0, const ushort_t* __restrict__ Wb,
    const ushort_t* __restrict__ Amix,
    const float* __restrict__ bf, const float* __restrict__ bg,
    int kb, int cur_len, int L) {
    __shared__ __align__(16) ushort_t ht[128][36];
    int j = blockIdx.y, eb = blockIdx.z, e = eb >> 3, ek = e * NBK + kb;
    int tid = threadIdx.x;
    int w = tid >> 6, lane = tid & 63;
    int l15 = lane & 15, lg = lane >> 4;
    int ot = w >> 1;
    int nloc0 = (w & 1) * 64;
    int nbase = blockIdx.x * 128;
    int t0 = 26 - cur_len + j;

    const ushort_t* WbE = Wb + (size_t)e * 14336;
    bf16x8 af_[7], ag_[7];
#pragma unroll
    for (int dt = 0; dt < 7; ++dt) {
        af_[dt] = *(const bf16x8*)(WbE + ((size_t)(dt * 2 + ot) * 16 + l15) * 32 + lg * 8);
        ag_[dt] = *(const bf16x8*)(WbE + 7168 + ((size_t)(dt * 2 + ot) * 16 + l15) * 32 + lg * 8);
    }
    float bfv[4], bgv[4];
#pragma unroll
    for (int r = 0; r < 4; ++r) {
        int o = ot * 16 + 4 * lg + r;
        bfv[r] = bf[ek * 32 + o];
        bgv[r] = bg[ek * 32 + o];
    }
    const ushort_t* xe = xb + ((size_t)eb * 26) * 512 * 32;
#pragma unroll
    for (int nt = 0; nt < 4; ++nt) {
        int nloc = nloc0 + nt * 16;
        int n0 = nbase + nloc;
        bf16x8 bfr[7];
#pragma unroll
        for (int dt = 0; dt < 7; ++dt)
            bfr[dt] = *(const bf16x8*)(xe + ((size_t)(t0 + dt) * 512 + n0 + l15) * 32 + lg * 8);
        f32x4 accf = {}, accg = {};
#pragma unroll
        for (int dt = 0; dt < 7; ++dt) {
            accf = __builtin_amdgcn_mfma_f32_16x16x32_bf16(af_[dt], bfr[dt], accf, 0, 0, 0);
            accg = __builtin_amdgcn_mfma_f32_16x16x32_bf16(ag_[dt], bfr[dt], accg, 0, 0, 0);
        }
        u16x4 q;
#pragma unroll
        for (int r = 0; r < 4; ++r) {
            float a = accf[r] + bfv[r];
            float b = accg[r] + bgv[r];
            q[r] = f2bf(tanhf(a) * (1.f / (1.f + expf(-b))));
        }
        *(u16x4*)&ht[nloc + l15][ot * 16 + 4 * lg] = q;
    }
    __syncthreads();

    // As = M_s @ h  (K=32, one MFMA per output frag)
    size_t ebj = (size_t)eb * L + j;
    const f32x4 zero = {};
    for (int s = w; s < 5; s += 4) {
        bf16x8 am[2];
        am[0] = *(const bf16x8*)(Amix + ((size_t)e * 32 + l15) * 160 + s * 32 + lg * 8);
        am[1] = *(const bf16x8*)(Amix + ((size_t)e * 32 + 16 + l15) * 160 + s * 32 + lg * 8);
#pragma unroll
        for (int cf = 0; cf < 8; ++cf) {
            bf16x8 bfrag = *(const bf16x8*)&ht[cf * 16 + l15][lg * 8];
            int nglob = nbase + cf * 16 + l15;
#pragma unroll
            for (int mf = 0; mf < 2; ++mf) {
                f32x4 a = __builtin_amdgcn_mfma_f32_16x16x32_bf16(am[mf], bfrag, zero, 0, 0, 0);
#pragma unroll
                for (int r = 0; r < 4; ++r) {
                    int co = mf * 16 + 4 * lg + r;
                    if (s == 0)
                        g0[(ebj * 32 + co) * 512 + nglob] = a[r];
                    else
                        Aprime[ebj * 65536 + (size_t)co * 2048 + (s - 1) * 512 + nglob] =
                            f2bf(a[r]);
                }
            }
        }
    }
}

// ---------------------------------------------------------------------------
// Fused K=2048 GEMM + x update: g = g0 + A'(32x2048) @ B'^T(512x2048);
// x[t] -= 0.25*(g + bsum); xb = bf16(x).
// grid (2 coltiles, L, 16 eb); 4 waves; wave covers 64 cols (wc0 = ct*256+w*64).
// A' chunk (32 rows x 64 k = 4KB) LDS-staged double-buffered (round-12 pattern).
__global__ __launch_bounds__(256) void k_gemmC(
    float* __restrict__ x, ushort_t* __restrict__ xbuf,
    const ushort_t* __restrict__ Aprime, const float* __restrict__ g0,
    const ushort_t* __restrict__ Bp, const float* __restrict__ bsum, int L) {
    __shared__ __align__(16) ushort_t Als[2][32][72];
    int ct = blockIdx.x, j = blockIdx.y, eb = blockIdx.z, e = eb >> 3;
    int tid = threadIdx.x, w = tid >> 6, lane = tid & 63;
    int l15 = lane & 15, lg = lane >> 4;
    int t = 26 - L + j;
    size_t ebj = (size_t)eb * L + j;
    const ushort_t* Ab = Aprime + ebj * 65536;
    int srow = tid >> 3;        // 0..31
    int sk8 = (tid & 7) * 8;    // 0..56
    const ushort_t* Asrc = Ab + (size_t)srow * 2048 + sk8;
    int wc0 = ct * 256 + w * 64;

    // acc init from g0
    f32x4 acc[2][4];
#pragma unroll
    for (int mf = 0; mf < 2; ++mf)
#pragma unroll
        for (int nf = 0; nf < 4; ++nf)
#pragma unroll
            for (int r = 0; r < 4; ++r) {
                int co = mf * 16 + 4 * lg + r;
                int n = wc0 + nf * 16 + l15;
                acc[mf][nf][r] = g0[(ebj * 32 + co) * 512 + n];
            }
    const ushort_t* Bcol[4];
#pragma unroll
    for (int nf = 0; nf < 4; ++nf)
        Bcol[nf] = Bp + (size_t)(wc0 + nf * 16 + l15) * 2048 + lg * 8;

    bf16x8 aN;
    {
        bf16x8 a0 = *(const bf16x8*)(Asrc);
        aN = *(const bf16x8*)(Asrc + 64);
        *(bf16x8*)&Als[0][srow][sk8] = a0;
    }
    __syncthreads();
#pragma unroll 2
    for (int ks = 0; ks < 32; ++ks) {
        int cur = ks & 1;
        int k0 = ks * 64;
        bf16x8 av[2][2], bv[4][2];
#pragma unroll
        for (int mf = 0; mf < 2; ++mf)
#pragma unroll
            for (int kk = 0; kk < 2; ++kk)
                av[mf][kk] = *(const bf16x8*)&Als[cur][mf * 16 + l15][kk * 32 + lg * 8];
#pragma unroll
        for (int nf = 0; nf < 4; ++nf)
#pragma unroll
            for (int kk = 0; kk < 2; ++kk)
                bv[nf][kk] = *(const bf16x8*)(Bcol[nf] + k0 + kk * 32);
        if (ks < 31) *(bf16x8*)&Als[cur ^ 1][srow][sk8] = aN;       // chunk ks+1
        if (ks < 30) aN = *(const bf16x8*)(Asrc + (ks + 2) * 64);   // chunk ks+2
#pragma unroll
        for (int kk = 0; kk < 2; ++kk)
#pragma unroll
            for (int mf = 0; mf < 2; ++mf)
#pragma unroll
                for (int nf = 0; nf < 4; ++nf)
                    acc[mf][nf] = __builtin_amdgcn_mfma_f32_16x16x32_bf16(
                        av[mf][kk], bv[nf][kk], acc[mf][nf], 0, 0, 0);
        __syncthreads();
    }
    // epilogue: x -= 0.25*(g + bsum); xb mirror
    float* xt = x + ((size_t)(eb * 26 + t) * 32) * 512;
    ushort_t* xbt = xbuf + ((size_t)(eb * 26 + t) * 512) * 32;
#pragma unroll
    for (int mf = 0; mf < 2; ++mf)
#pragma unroll
        for (int nf = 0; nf < 4; ++nf) {
            int n = wc0 + nf * 16 + l15;
            u16x4 q;
#pragma unroll
            for (int r = 0; r < 4; ++r) {
                int co = mf * 16 + 4 * lg + r;
                float nv = xt[(size_t)co * 512 + n] -
                           0.25f * (acc[mf][nf][r] + bsum[e * 32 + co]);
                xt[(size_t)co * 512 + n] = nv;
                q[r] = f2bf(nv);
            }
            *(u16x4*)(xbt + (size_t)n * 32 + mf * 16 + 4 * lg) = q;
        }
}

// ---------------------------------------------------------------------------
__global__ __launch_bounds__(256) void k_lnstats(const float* __restrict__ x,
                                                 float* __restrict__ stats) {
    int eb = blockIdx.x;
    const float* p = x + ((size_t)(eb * 26 + 24) * 32) * 512;
    float s = 0.f, s2 = 0.f;
    for (int i = threadIdx.x; i < 32768; i += 256) {
        float v = p[i];
        s += v;
        s2 += v * v;
    }
    for (int off = 32; off; off >>= 1) {
        s += __shfl_down(s, off);
        s2 += __shfl_down(s2, off);
    }
    __shared__ float r1[4], r2[4];
    if ((threadIdx.x & 63) == 0) {
        r1[threadIdx.x >> 6] = s;
        r2[threadIdx.x >> 6] = s2;
    }
    __syncthreads();
    if (threadIdx.x == 0) {
        float S = r1[0] + r1[1] + r1[2] + r1[3];
        float S2 = r2[0] + r2[1] + r2[2] + r2[3];
        float mu = S / 32768.f;
        float var = S2 / 32768.f - mu * mu;
        stats[eb * 2] = mu;
        stats[eb * 2 + 1] = rsqrtf(var + 1e-5f);
    }
}

// ---------------------------------------------------------------------------
__global__ __launch_bounds__(256) void k_heads_mfma(
    const ushort_t* __restrict__ xb, const float* __restrict__ stats,
    float* __restrict__ bkc, float* __restrict__ acc,
    const ushort_t* __restrict__ Whd, const float* __restrict__ rS,
    const float* __restrict__ bb1, const float* __restrict__ bb2,
    const float* __restrict__ bfc1, const float* __restrict__ bfc2,
    int kb) {
    __shared__ __align__(16) ushort_t lds[4][64][72];
    int w = blockIdx.y, eb = blockIdx.z;
    int e = eb >> 3, ek = e * NBK + kb;
    int tid = threadIdx.x, wv = tid >> 6, lane = tid & 63;
    int l15 = lane & 15, lg = lane >> 4;
    int n0 = blockIdx.x * 256 + wv * 64;
    float mu = stats[eb * 2], rsv = stats[eb * 2 + 1];
    const ushort_t* Wh = Whd + (size_t)e * 6144;
    const ushort_t* xrow = xb + ((size_t)(eb * 26 + 24 + w) * 512) * 32;

#pragma unroll
    for (int head = 0; head < 2; ++head) {
        if (head == 1 && w == 0) break;  // fc only for w==1
        int woff = head ? 3072 : 0;
        const float* b1 = head ? bfc1 : bb1;
        const float* b2 = head ? bfc2 : bb2;
        const float* rs1 = rS + e * 128 + (head ? 64 : 0);
        bf16x8 a1[4];
#pragma unroll
        for (int rt = 0; rt < 4; ++rt)
            a1[rt] = *(const bf16x8*)(Wh + woff + (size_t)(rt * 16 + l15) * 32 + lg * 8);
        float be[4][4];
#pragma unroll
        for (int rt = 0; rt < 4; ++rt)
#pragma unroll
            for (int r = 0; r < 4; ++r) {
                int d = rt * 16 + 4 * lg + r;
                be[rt][r] = b1[ek * 64 + d] - rsv * mu * rs1[d];
            }
#pragma unroll
        for (int nt = 0; nt < 4; ++nt) {
            bf16x8 bv = *(const bf16x8*)(xrow + (size_t)(n0 + nt * 16 + l15) * 32 + lg * 8);
            f32x4 ac[4] = {};
#pragma unroll
            for (int rt = 0; rt < 4; ++rt)
                ac[rt] = __builtin_amdgcn_mfma_f32_16x16x32_bf16(a1[rt], bv, ac[rt], 0, 0, 0);
#pragma unroll
            for (int rt = 0; rt < 4; ++rt)
#pragma unroll
                for (int r = 0; r < 4; ++r) {
                    float hv = fmaxf(rsv * ac[rt][r] + be[rt][r], 0.f);
                    lds[wv][nt * 16 + l15][rt * 16 + 4 * lg + r] = f2bf(hv);
                }
        }
        bf16x8 a2[2];
        a2[0] = *(const bf16x8*)(Wh + woff + 2048 + (size_t)l15 * 64 + lg * 8);
        a2[1] = *(const bf16x8*)(Wh + woff + 2048 + (size_t)l15 * 64 + 32 + lg * 8);
        float b2v[4];
#pragma unroll
        for (int r = 0; r < 4; ++r) {
            int s = 4 * lg + r;
            b2v[r] = (s < 12) ? b2[ek * 12 + s] : 0.f;
        }
#pragma unroll
        for (int nt = 0; nt < 4; ++nt) {
            bf16x8 b0 = *(const bf16x8*)&lds[wv][nt * 16 + l15][lg * 8];
            bf16x8 b1f = *(const bf16x8*)&lds[wv][nt * 16 + l15][32 + lg * 8];
            f32x4 ac2 = {};
            ac2 = __builtin_amdgcn_mfma_f32_16x16x32_bf16(a2[0], b0, ac2, 0, 0, 0);
            ac2 = __builtin_amdgcn_mfma_f32_16x16x32_bf16(a2[1], b1f, ac2, 0, 0, 0);
#pragma unroll
            for (int r = 0; r < 4; ++r) {
                int s = 4 * lg + r;
                if (s < 12) {
                    int n = n0 + nt * 16 + l15;
                    float val = ac2[r] + b2v[r];
                    if (head == 0)
                        bkc[((size_t)(eb * 12 + s) * 512 + n) * 2 + w] -= val;
                    else
                        acc[(size_t)(eb * 12 + s) * 512 + n] += val;
                }
            }
        }
    }
}

// ---------------------------------------------------------------------------
__global__ __launch_bounds__(256) void k_final(const float* __restrict__ acc,
                                               const float* __restrict__ ew,
                                               float* __restrict__ out) {
    int i = blockIdx.x * 256 + threadIdx.x;  // 49152
    out[i] = ew[0] * acc[i] + ew[1] * acc[49152 + i];
}

// ---------------------------------------------------------------------------
extern "C" void kernel_launch(void* const* d_in, const int* in_sizes, int n_in,
                              void* d_out, int out_size, void* d_ws, size_t ws_size,
                              hipStream_t stream) {
    const float* X    = (const float*)d_in[0];
    const float* adj  = (const float*)d_in[1];
    const float* ew   = (const float*)d_in[2];
    const float* Wst  = (const float*)d_in[3];
    const float* bst  = (const float*)d_in[4];
    const float* Wf2  = (const float*)d_in[5];
    const float* Wf3  = (const float*)d_in[6];
    const float* Wf5  = (const float*)d_in[7];
    const float* Wf7  = (const float*)d_in[8];
    const float* bf   = (const float*)d_in[9];
    const float* Wg2  = (const float*)d_in[10];
    const float* Wg3  = (const float*)d_in[11];
    const float* Wg5  = (const float*)d_in[12];
    const float* Wg7  = (const float*)d_in[13];
    const float* bg   = (const float*)d_in[14];
    const float* Wgc1 = (const float*)d_in[15];
    const float* bgc1 = (const float*)d_in[16];
    const float* Wgc2 = (const float*)d_in[17];
    const float* bgc2 = (const float*)d_in[18];
    const float* Wb1  = (const float*)d_in[19];
    const float* bb1  = (const float*)d_in[20];
    const float* Wb2  = (const float*)d_in[21];
    const float* bb2  = (const float*)d_in[22];
    const float* Wfc1 = (const float*)d_in[23];
    const float* bfc1 = (const float*)d_in[24];
    const float* Wfc2 = (const float*)d_in[25];
    const float* bfc2 = (const float*)d_in[26];

    float* ws = (float*)d_ws;
    size_t off = 0;
    auto alloc = [&](size_t nf) { float* p = ws + off; off += nf; return p; };
    float* di    = alloc(512);
    ushort_t* Bp = (ushort_t*)alloc(512 * 2048 / 2);       // packed B' (1M ushorts)
    float* bkc   = alloc((size_t)EE * BATCH * 12 * 512 * 2);
    float* acc   = alloc((size_t)EE * BATCH * 12 * 512);
    float* stats = alloc(32);
    ushort_t* Amix = (ushort_t*)alloc(2 * 32 * 160 / 2);
    float* bsum  = alloc(64);
    ushort_t* Wb = (ushort_t*)alloc(14336);
    ushort_t* Whd = (ushort_t*)alloc(6144);
    float* rSb   = alloc(256);
    float* x     = alloc((size_t)16 * 26 * 32 * 512);
    ushort_t* xb = (ushort_t*)alloc((size_t)16 * 26 * 512 * 32 / 2);
    ushort_t* Aprime = (ushort_t*)alloc((size_t)320 * 32 * 2048 / 2);  // 21M ushorts
    float* g0    = alloc((size_t)320 * 32 * 512);
    if (off * sizeof(float) > ws_size) return;  // workspace too small: bail

    // Graph normalization + An^2 precompute (into packed B')
    k_rowsum<<<512, 256, 0, stream>>>(adj, di);
    k_norm<<<1024, 256, 0, stream>>>(adj, di, Bp);
    k_An2<<<dim3(2, 8), 256, 0, stream>>>(Bp);

    // Residual init (both experts start from X) + output accumulator zero
    hipMemcpyAsync(bkc, X, (size_t)98304 * 4, hipMemcpyDeviceToDevice, stream);
    hipMemcpyAsync(bkc + 98304, X, (size_t)98304 * 4, hipMemcpyDeviceToDevice, stream);
    hipMemsetAsync(acc, 0, (size_t)EE * BATCH * 12 * 512 * 4, stream);

    for (int kb = 0; kb < NBK; ++kb) {
        k_prep<<<116, 256, 0, stream>>>(Wf2, Wf3, Wf5, Wf7, Wg2, Wg3, Wg5, Wg7, Wb,
                                        Wgc1, bgc1, Wgc2, bgc2, Amix, bsum,
                                        Wb1, Wb2, Wfc1, Wfc2, Whd, rSb, kb);
        k_start<<<dim3(2, 26, 16), 256, 0, stream>>>(bkc, x, xb, Wst, bst, kb);
        int cur = 26;
        for (int it = 0; it < 4; ++it) {
            int L = cur - 6;
            k_incept2<<<dim3(4, L, 16), 256, 0, stream>>>(
                xb, Aprime, g0, Wb, Amix, bf, bg, kb, cur, L);
            k_gemmC<<<dim3(2, L, 16), 256, 0, stream>>>(
                x, xb, Aprime, g0, Bp, bsum, L);
            cur -= 6;
        }
        k_lnstats<<<16, 256, 0, stream>>>(x, stats);
        k_heads_mfma<<<dim3(2, 2, 16), 256, 0, stream>>>(xb, stats, bkc, acc, Whd, rSb,
                                                         bb1, bb2, bfc1, bfc2, kb);
    }
    k_final<<<192, 256, 0, stream>>>(acc, ew, (float*)d_out);
}

// Round 14
// 785.107 us; speedup vs baseline: 1.1856x; 1.1856x over previous
//
#include <hip/hip_runtime.h>
#include <stddef.h>

// Problem constants (E=2 experts, NB=2 blocks, B=8 batch, N=512 nodes)
#define EE 2
#define NBK 2
#define BATCH 8

typedef unsigned short ushort_t;
typedef short bf16x8 __attribute__((ext_vector_type(8)));
typedef float f32x4 __attribute__((ext_vector_type(4)));
typedef unsigned short u16x4 __attribute__((ext_vector_type(4)));

__device__ __forceinline__ ushort_t f2bf(float f) {
    unsigned int u = __float_as_uint(f);
    u += 0x7FFF + ((u >> 16) & 1);
    return (ushort_t)(u >> 16);
}
__device__ __forceinline__ float bf2f(ushort_t h) {
    return __uint_as_float(((unsigned int)h) << 16);
}

// ---------------------------------------------------------------------------
__global__ __launch_bounds__(256) void k_rowsum(const float* __restrict__ adj,
                                                float* __restrict__ di) {
    int v = blockIdx.x;
    int tid = threadIdx.x;
    float s = 0.f;
    for (int w = tid; w < 512; w += 256)
        s += adj[v * 512 + w] + (w == v ? 1.f : 0.f);
    for (int off = 32; off; off >>= 1) s += __shfl_down(s, off);
    __shared__ float red[4];
    if ((tid & 63) == 0) red[tid >> 6] = s;
    __syncthreads();
    if (tid == 0) {
        float t = red[0] + red[1] + red[2] + red[3];
        di[v] = rsqrtf(t);
    }
}

__global__ __launch_bounds__(256) void k_norm(const float* __restrict__ adj,
                                              const float* __restrict__ di,
                                              ushort_t* __restrict__ An,
                                              ushort_t* __restrict__ AnT) {
    int idx = blockIdx.x * 256 + threadIdx.x;  // 0..262143
    int v = idx >> 9, w = idx & 511;
    float a = adj[idx] + (v == w ? 1.f : 0.f);
    ushort_t val = f2bf(di[v] * a * di[w]);
    An[idx] = val;
    AnT[w * 512 + v] = val;
}

// ---------------------------------------------------------------------------
// An2 = An·An (row-major); An2T = (An2)^T.
__global__ __launch_bounds__(256) void k_An2(
    const ushort_t* __restrict__ Anb, const ushort_t* __restrict__ AnTb,
    ushort_t* __restrict__ An2, ushort_t* __restrict__ An2T) {
    int tid = threadIdx.x;
    int w = tid >> 6, lane = tid & 63;
    int l15 = lane & 15, lg = lane >> 4;
    int wbase = blockIdx.x * 256 + w * 64;
    int n0 = blockIdx.y * 64;
    f32x4 acc[4][4] = {};
    const ushort_t* Ap = Anb + (size_t)(wbase + l15) * 512 + lg * 8;
    const ushort_t* Bp = AnTb + (size_t)(n0 + l15) * 512 + lg * 8;
    bf16x8 avC[4], bvC[4], avN[4], bvN[4];
#pragma unroll
    for (int i = 0; i < 4; ++i) {
        avC[i] = *(const bf16x8*)(Ap + (size_t)i * 16 * 512);
        bvC[i] = *(const bf16x8*)(Bp + (size_t)i * 16 * 512);
    }
#pragma unroll 2
    for (int k0 = 0; k0 < 512; k0 += 32) {
        int kn = k0 + 32;
        if (kn < 512) {
#pragma unroll
            for (int i = 0; i < 4; ++i) {
                avN[i] = *(const bf16x8*)(Ap + (size_t)i * 16 * 512 + kn);
                bvN[i] = *(const bf16x8*)(Bp + (size_t)i * 16 * 512 + kn);
            }
        }
#pragma unroll
        for (int mf = 0; mf < 4; ++mf)
#pragma unroll
            for (int nf = 0; nf < 4; ++nf)
                acc[mf][nf] = __builtin_amdgcn_mfma_f32_16x16x32_bf16(
                    avC[mf], bvC[nf], acc[mf][nf], 0, 0, 0);
#pragma unroll
        for (int i = 0; i < 4; ++i) { avC[i] = avN[i]; bvC[i] = bvN[i]; }
    }
#pragma unroll
    for (int mf = 0; mf < 4; ++mf)
#pragma unroll
        for (int nf = 0; nf < 4; ++nf) {
            int col = n0 + 16 * nf + l15;
            int row0 = wbase + 16 * mf + 4 * lg;
            u16x4 q;
#pragma unroll
            for (int r = 0; r < 4; ++r) {
                ushort_t vb = f2bf(acc[mf][nf][r]);
                q[r] = vb;
                An2[(size_t)(row0 + r) * 512 + col] = vb;
            }
            *(u16x4*)(An2T + (size_t)col * 512 + row0) = q;
        }
}

// ---------------------------------------------------------------------------
// Fused per-kb weight prep: blocks 0..111 -> inception Weff; 112,113 ->
// mix matrices (e = bx-112); 114,115 -> head weights (e = bx-114).
__global__ __launch_bounds__(256) void k_prep(
    const float* __restrict__ Wf2, const float* __restrict__ Wf3,
    const float* __restrict__ Wf5, const float* __restrict__ Wf7,
    const float* __restrict__ Wg2, const float* __restrict__ Wg3,
    const float* __restrict__ Wg5, const float* __restrict__ Wg7,
    ushort_t* __restrict__ Wb,
    const float* __restrict__ Wgc1, const float* __restrict__ bgc1,
    const float* __restrict__ Wgc2, const float* __restrict__ bgc2,
    ushort_t* __restrict__ Amix, float* __restrict__ bsum,
    const float* __restrict__ Wb1, const float* __restrict__ Wb2,
    const float* __restrict__ Wfc1, const float* __restrict__ Wfc2,
    ushort_t* __restrict__ Whd, float* __restrict__ rS, int kb) {
    int bx = blockIdx.x;
    if (bx < 112) {
        int idx = bx * 256 + threadIdx.x;  // 28672 total
        if (idx >= 2 * 2 * 7 * 2 * 16 * 32) return;
        int c = idx & 31;
        int t1 = idx >> 5;
        int o16 = t1 & 15;
        int t2 = t1 >> 4;
        int ot = t2 & 1;
        int t3 = t2 >> 1;
        int dt = t3 % 7;
        int t4 = t3 / 7;
        int fg = t4 & 1;
        int e = t4 >> 1;
        int ek = e * NBK + kb;
        int o = ot * 16 + o16;
        int grp = o >> 3, oo = o & 7;
        const int kstab[4] = {2, 3, 5, 7};
        int ks = kstab[grp];
        int lo = 7 - ks;
        float val = 0.f;
        if (dt >= lo) {
            int di = dt - lo;
            const float* W;
            if (grp == 0) W = (fg ? Wg2 : Wf2) + (size_t)ek * 512 + oo * 64 + c * 2 + di;
            else if (grp == 1) W = (fg ? Wg3 : Wf3) + (size_t)ek * 768 + oo * 96 + c * 3 + di;
            else if (grp == 2) W = (fg ? Wg5 : Wf5) + (size_t)ek * 1280 + oo * 160 + c * 5 + di;
            else W = (fg ? Wg7 : Wf7) + (size_t)ek * 1792 + oo * 224 + c * 7 + di;
            val = *W;
        }
        Wb[idx] = f2bf(val);
    } else if (bx < 114) {
        int e = bx - 112;
        int ek = e * NBK + kb;
        const float* W1 = Wgc1 + (size_t)ek * 32 * 96;
        const float* W2 = Wgc2 + (size_t)ek * 32 * 96;
        for (int idx = threadIdx.x; idx < 32 * 160; idx += 256) {
            int co = idx / 160, k = idx % 160;
            int slot = k >> 5, cp = k & 31;
            float val;
            if (slot == 0)
                val = W1[co * 96 + cp] + W1[co * 96 + 32 + cp] + W1[co * 96 + 64 + cp] +
                      W2[co * 96 + cp] + W2[co * 96 + 32 + cp] + W2[co * 96 + 64 + cp];
            else if (slot == 1) val = 0.5f * W1[co * 96 + 32 + cp] + W1[co * 96 + 64 + cp];
            else if (slot == 2) val = 0.25f * W1[co * 96 + 64 + cp];
            else if (slot == 3) val = 0.5f * W2[co * 96 + 32 + cp] + W2[co * 96 + 64 + cp];
            else val = 0.25f * W2[co * 96 + 64 + cp];
            Amix[((size_t)e * 32 + co) * 160 + k] = f2bf(val);
        }
        if (threadIdx.x < 32)
            bsum[e * 32 + threadIdx.x] =
                bgc1[ek * 32 + threadIdx.x] + bgc2[ek * 32 + threadIdx.x];
    } else {
        int e = bx - 114;
        int ek = e * NBK + kb;
        ushort_t* Wh = Whd + (size_t)e * 6144;
        for (int i = threadIdx.x; i < 2048; i += 256)
            Wh[i] = f2bf(Wb1[(size_t)ek * 2048 + i]);
        for (int i = threadIdx.x; i < 1024; i += 256) {
            int r = i >> 6, d = i & 63;
            Wh[2048 + i] = f2bf(r < 12 ? Wb2[(size_t)ek * 768 + r * 64 + d] : 0.f);
        }
        for (int i = threadIdx.x; i < 2048; i += 256)
            Wh[3072 + i] = f2bf(Wfc1[(size_t)ek * 2048 + i]);
        for (int i = threadIdx.x; i < 1024; i += 256) {
            int r = i >> 6, d = i & 63;
            Wh[5120 + i] = f2bf(r < 12 ? Wfc2[(size_t)ek * 768 + r * 64 + d] : 0.f);
        }
        if (threadIdx.x < 64) {
            int d = threadIdx.x;
            float s1 = 0.f, s2 = 0.f;
            for (int c = 0; c < 32; ++c) {
                s1 += Wb1[(size_t)ek * 2048 + d * 32 + c];
                s2 += Wfc1[(size_t)ek * 2048 + d * 32 + c];
            }
            rS[e * 128 + d] = s1;
            rS[e * 128 + 64 + d] = s2;
        }
    }
}

// ---------------------------------------------------------------------------
// start: writes x fp32 [eb][t][c][n] and bf16 mirror xb [eb][t][n][c]
__global__ __launch_bounds__(256) void k_start(const float* __restrict__ bkc,
                                               float* __restrict__ x,
                                               ushort_t* __restrict__ xb,
                                               const float* __restrict__ Wst,
                                               const float* __restrict__ bst,
                                               int kb) {
    int n = blockIdx.x * 256 + threadIdx.x;
    int t = blockIdx.y;
    int eb = blockIdx.z;
    int e = eb >> 3;
    int ek = e * NBK + kb;
    const float* Wp = Wst + (size_t)ek * 32 * 2;
    const float* bp = bst + (size_t)ek * 32;
    float in0 = 0.f, in1 = 0.f;
    if (t >= 14) {
        const float* p = bkc + ((size_t)(eb * 12 + (t - 14)) * 512 + n) * 2;
        in0 = p[0];
        in1 = p[1];
    }
    float* xo = x + ((size_t)(eb * 26 + t) * 32) * 512 + n;
    ushort_t tmp[32];
#pragma unroll
    for (int c = 0; c < 32; ++c) {
        float v = bp[c] + Wp[c * 2] * in0 + Wp[c * 2 + 1] * in1;
        xo[(size_t)c * 512] = v;
        tmp[c] = f2bf(v);
    }
    ushort_t* xbp = xb + ((size_t)(eb * 26 + t) * 512 + n) * 32;
#pragma unroll
    for (int q = 0; q < 4; ++q)
        *(bf16x8*)(xbp + q * 8) = *(bf16x8*)(tmp + q * 8);
}

// ---------------------------------------------------------------------------
// MFMA inception: writes h_old [col][n] (GEMM A operand) + buf5 slot0 (Y)
__global__ __launch_bounds__(256) void k_incept_mfma(
    const ushort_t* __restrict__ xb, ushort_t* __restrict__ h,
    ushort_t* __restrict__ buf5, const ushort_t* __restrict__ Wb,
    const float* __restrict__ bf, const float* __restrict__ bg,
    int kb, int cur_len, int L) {
    int j = blockIdx.y, eb = blockIdx.z, e = eb >> 3, ek = e * NBK + kb;
    int tid = threadIdx.x;
    int w = tid >> 6, lane = tid & 63;
    int l15 = lane & 15, lg = lane >> 4;
    int ot = w >> 1;
    int n0base = blockIdx.x * 128 + (w & 1) * 64;
    int t0 = 26 - cur_len + j;

    const ushort_t* WbE = Wb + (size_t)e * 14336;
    bf16x8 af_[7], ag_[7];
#pragma unroll
    for (int dt = 0; dt < 7; ++dt) {
        af_[dt] = *(const bf16x8*)(WbE + ((size_t)(dt * 2 + ot) * 16 + l15) * 32 + lg * 8);
        ag_[dt] = *(const bf16x8*)(WbE + 7168 + ((size_t)(dt * 2 + ot) * 16 + l15) * 32 + lg * 8);
    }
    float bfv[4], bgv[4];
#pragma unroll
    for (int r = 0; r < 4; ++r) {
        int o = ot * 16 + 4 * lg + r;
        bfv[r] = bf[ek * 32 + o];
        bgv[r] = bg[ek * 32 + o];
    }
    size_t colbase = ((size_t)eb * L + j) * 32;
    size_t rowb = ((size_t)eb * L + j) * 512;
    const ushort_t* xe = xb + ((size_t)eb * 26) * 512 * 32;
#pragma unroll
    for (int nt = 0; nt < 4; ++nt) {
        int n0 = n0base + nt * 16;
        // batch all 7 window loads up-front (ILP), then run the MFMA chain
        bf16x8 bfr[7];
#pragma unroll
        for (int dt = 0; dt < 7; ++dt)
            bfr[dt] = *(const bf16x8*)(xe + ((size_t)(t0 + dt) * 512 + n0 + l15) * 32 + lg * 8);
        f32x4 accf = {}, accg = {};
#pragma unroll
        for (int dt = 0; dt < 7; ++dt) {
            accf = __builtin_amdgcn_mfma_f32_16x16x32_bf16(af_[dt], bfr[dt], accf, 0, 0, 0);
            accg = __builtin_amdgcn_mfma_f32_16x16x32_bf16(ag_[dt], bfr[dt], accg, 0, 0, 0);
        }
        u16x4 q;
#pragma unroll
        for (int r = 0; r < 4; ++r) {
            float a = accf[r] + bfv[r];
            float b = accg[r] + bgv[r];
            float hv = tanhf(a) * (1.f / (1.f + expf(-b)));
            ushort_t hb = f2bf(hv);
            q[r] = hb;
            int o = ot * 16 + 4 * lg + r;
            h[(colbase + o) * 512 + n0 + l15] = hb;
        }
        *(u16x4*)(buf5 + (rowb + n0 + l15) * 160 + ot * 16 + 4 * lg) = q;
    }
}

// ---------------------------------------------------------------------------
// Dual-slot NT GEMM from h with LDS-staged B tiles (double-buffered, padded).
// z=0: slots 1,2 (B = An, An2); z=1: slots 3,4 (B = AnT, An2T).
// Block = 4 waves x 64 rows = 256 rows, 64 cols; per K-step the shared
// A-fragments feed 32 MFMAs (2 B-matrices) instead of 16 -> stall amortized.
__global__ __launch_bounds__(256) void k_gemm4(
    const ushort_t* __restrict__ A,
    const ushort_t* __restrict__ B0, const ushort_t* __restrict__ B1,
    const ushort_t* __restrict__ B2, const ushort_t* __restrict__ B3,
    ushort_t* __restrict__ buf5) {
    __shared__ __align__(16) ushort_t Bs[2][2][64][36];  // [dbuf][which][col][k]
    int z = blockIdx.z;
    const ushort_t* Ba = z ? B2 : B0;
    const ushort_t* Bb = z ? B3 : B1;
    int slot0 = z ? 3 : 1;
    int tid = threadIdx.x;
    int w = tid >> 6, lane = tid & 63;
    int l15 = lane & 15, lg = lane >> 4;
    int wbase = blockIdx.x * 256 + w * 64;
    int n0 = blockIdx.y * 64;
    int scol = tid >> 2;          // 0..63
    int skq = (tid & 3) * 8;      // 0,8,16,24
    const ushort_t* BsrcA = Ba + (size_t)(n0 + scol) * 512 + skq;
    const ushort_t* BsrcB = Bb + (size_t)(n0 + scol) * 512 + skq;
    const ushort_t* Ap = A + (size_t)(wbase + l15) * 512 + lg * 8;
    f32x4 acc[2][4][4] = {};
    bf16x8 bregA, bregB;
    {
        *(bf16x8*)&Bs[0][0][scol][skq] = *(const bf16x8*)(BsrcA);
        *(bf16x8*)&Bs[0][1][scol][skq] = *(const bf16x8*)(BsrcB);
        bregA = *(const bf16x8*)(BsrcA + 32);
        bregB = *(const bf16x8*)(BsrcB + 32);
    }
    __syncthreads();
#pragma unroll 2
    for (int ks = 0; ks < 16; ++ks) {
        int cur = ks & 1;
        int k0 = ks * 32;
        bf16x8 av[4], bvA[4], bvB[4];
#pragma unroll
        for (int mf = 0; mf < 4; ++mf)
            av[mf] = *(const bf16x8*)(Ap + (size_t)mf * 16 * 512 + k0);
#pragma unroll
        for (int nf = 0; nf < 4; ++nf) {
            bvA[nf] = *(const bf16x8*)&Bs[cur][0][16 * nf + l15][lg * 8];
            bvB[nf] = *(const bf16x8*)&Bs[cur][1][16 * nf + l15][lg * 8];
        }
        if (ks < 15) {
            *(bf16x8*)&Bs[cur ^ 1][0][scol][skq] = bregA;  // chunk ks+1
            *(bf16x8*)&Bs[cur ^ 1][1][scol][skq] = bregB;
        }
        if (ks < 14) {
            bregA = *(const bf16x8*)(BsrcA + (ks + 2) * 32);  // chunk ks+2
            bregB = *(const bf16x8*)(BsrcB + (ks + 2) * 32);
        }
#pragma unroll
        for (int mf = 0; mf < 4; ++mf)
#pragma unroll
            for (int nf = 0; nf < 4; ++nf) {
                acc[0][mf][nf] = __builtin_amdgcn_mfma_f32_16x16x32_bf16(
                    av[mf], bvA[nf], acc[0][mf][nf], 0, 0, 0);
                acc[1][mf][nf] = __builtin_amdgcn_mfma_f32_16x16x32_bf16(
                    av[mf], bvB[nf], acc[1][mf][nf], 0, 0, 0);
            }
        __syncthreads();
    }
#pragma unroll
    for (int s = 0; s < 2; ++s) {
        int slot = slot0 + s;
#pragma unroll
        for (int mf = 0; mf < 4; ++mf) {
            int jeb = (wbase >> 5) + (mf >> 1);
            int c0 = 16 * (mf & 1) + 4 * lg;
#pragma unroll
            for (int nf = 0; nf < 4; ++nf) {
                int col = n0 + 16 * nf + l15;
                u16x4 q;
#pragma unroll
                for (int r = 0; r < 4; ++r) q[r] = f2bf(acc[s][mf][nf][r]);
                *(u16x4*)(buf5 + ((size_t)jeb * 512 + col) * 160 + slot * 32 + c0) = q;
            }
        }
    }
}

// ---------------------------------------------------------------------------
// MFMA combine: g = Amix @ buf5^T + bsum; x -= 0.25*g; xb = bf16(x)
__global__ __launch_bounds__(256) void k_combine_mfma(
    float* __restrict__ x, ushort_t* __restrict__ xb,
    const ushort_t* __restrict__ buf5, const ushort_t* __restrict__ Amix,
    const float* __restrict__ bsum, int L) {
    int j = blockIdx.x, eb = blockIdx.y, e = eb >> 3;
    int tid = threadIdx.x, wv = tid >> 6, lane = tid & 63;
    int l15 = lane & 15, lg = lane >> 4;
    int t = 26 - L + j;
    const ushort_t* Ae = Amix + (size_t)e * 32 * 160;
    bf16x8 a[2][5];
#pragma unroll
    for (int ct = 0; ct < 2; ++ct)
#pragma unroll
        for (int ks = 0; ks < 5; ++ks)
            a[ct][ks] = *(const bf16x8*)(Ae + (size_t)(ct * 16 + l15) * 160 + ks * 32 + lg * 8);
    float bs[2][4];
#pragma unroll
    for (int ct = 0; ct < 2; ++ct)
#pragma unroll
        for (int r = 0; r < 4; ++r) bs[ct][r] = bsum[e * 32 + ct * 16 + 4 * lg + r];
    size_t rowb = ((size_t)eb * L + j) * 512;
    size_t xtb = ((size_t)(eb * 26 + t) * 32) * 512;
    ushort_t* xbt = xb + ((size_t)(eb * 26 + t) * 512) * 32;
#pragma unroll
    for (int nt = 0; nt < 8; ++nt) {
        int n = wv * 128 + nt * 16 + l15;
        const ushort_t* bp = buf5 + (rowb + n) * 160 + lg * 8;
        bf16x8 b[5];
#pragma unroll
        for (int ks = 0; ks < 5; ++ks) b[ks] = *(const bf16x8*)(bp + ks * 32);
        f32x4 acc[2] = {};
#pragma unroll
        for (int ks = 0; ks < 5; ++ks) {
            acc[0] = __builtin_amdgcn_mfma_f32_16x16x32_bf16(a[0][ks], b[ks], acc[0], 0, 0, 0);
            acc[1] = __builtin_amdgcn_mfma_f32_16x16x32_bf16(a[1][ks], b[ks], acc[1], 0, 0, 0);
        }
#pragma unroll
        for (int ct = 0; ct < 2; ++ct) {
            u16x4 q;
#pragma unroll
            for (int r = 0; r < 4; ++r) {
                int co = ct * 16 + 4 * lg + r;
                float* xp = x + xtb + (size_t)co * 512 + n;
                float nv = *xp - 0.25f * (acc[ct][r] + bs[ct][r]);
                *xp = nv;
                q[r] = f2bf(nv);
            }
            *(u16x4*)(xbt + (size_t)n * 32 + ct * 16 + 4 * lg) = q;
        }
    }
}

// ---------------------------------------------------------------------------
__global__ __launch_bounds__(256) void k_lnstats(const float* __restrict__ x,
                                                 float* __restrict__ stats) {
    int eb = blockIdx.x;
    const float* p = x + ((size_t)(eb * 26 + 24) * 32) * 512;
    float s = 0.f, s2 = 0.f;
    for (int i = threadIdx.x; i < 32768; i += 256) {
        float v = p[i];
        s += v;
        s2 += v * v;
    }
    for (int off = 32; off; off >>= 1) {
        s += __shfl_down(s, off);
        s2 += __shfl_down(s2, off);
    }
    __shared__ float r1[4], r2[4];
    if ((threadIdx.x & 63) == 0) {
        r1[threadIdx.x >> 6] = s;
        r2[threadIdx.x >> 6] = s2;
    }
    __syncthreads();
    if (threadIdx.x == 0) {
        float S = r1[0] + r1[1] + r1[2] + r1[3];
        float S2 = r2[0] + r2[1] + r2[2] + r2[3];
        float mu = S / 32768.f;
        float var = S2 / 32768.f - mu * mu;
        stats[eb * 2] = mu;
        stats[eb * 2 + 1] = rsqrtf(var + 1e-5f);
    }
}

// ---------------------------------------------------------------------------
__global__ __launch_bounds__(256) void k_heads_mfma(
    const ushort_t* __restrict__ xb, const float* __restrict__ stats,
    float* __restrict__ bkc, float* __restrict__ acc,
    const ushort_t* __restrict__ Whd, const float* __restrict__ rS,
    const float* __restrict__ bb1, const float* __restrict__ bb2,
    const float* __restrict__ bfc1, const float* __restrict__ bfc2,
    int kb) {
    __shared__ __align__(16) ushort_t lds[4][64][72];
    int w = blockIdx.y, eb = blockIdx.z;
    int e = eb >> 3, ek = e * NBK + kb;
    int tid = threadIdx.x, wv = tid >> 6, lane = tid & 63;
    int l15 = lane & 15, lg = lane >> 4;
    int n0 = blockIdx.x * 256 + wv * 64;
    float mu = stats[eb * 2], rsv = stats[eb * 2 + 1];
    const ushort_t* Wh = Whd + (size_t)e * 6144;
    const ushort_t* xrow = xb + ((size_t)(eb * 26 + 24 + w) * 512) * 32;

#pragma unroll
    for (int head = 0; head < 2; ++head) {
        if (head == 1 && w == 0) break;  // fc only for w==1
        int woff = head ? 3072 : 0;
        const float* b1 = head ? bfc1 : bb1;
        const float* b2 = head ? bfc2 : bb2;
        const float* rs1 = rS + e * 128 + (head ? 64 : 0);
        bf16x8 a1[4];
#pragma unroll
        for (int rt = 0; rt < 4; ++rt)
            a1[rt] = *(const bf16x8*)(Wh + woff + (size_t)(rt * 16 + l15) * 32 + lg * 8);
        float be[4][4];
#pragma unroll
        for (int rt = 0; rt < 4; ++rt)
#pragma unroll
            for (int r = 0; r < 4; ++r) {
                int d = rt * 16 + 4 * lg + r;
                be[rt][r] = b1[ek * 64 + d] - rsv * mu * rs1[d];
            }
#pragma unroll
        for (int nt = 0; nt < 4; ++nt) {
            bf16x8 bv = *(const bf16x8*)(xrow + (size_t)(n0 + nt * 16 + l15) * 32 + lg * 8);
            f32x4 ac[4] = {};
#pragma unroll
            for (int rt = 0; rt < 4; ++rt)
                ac[rt] = __builtin_amdgcn_mfma_f32_16x16x32_bf16(a1[rt], bv, ac[rt], 0, 0, 0);
#pragma unroll
            for (int rt = 0; rt < 4; ++rt)
#pragma unroll
                for (int r = 0; r < 4; ++r) {
                    float hv = fmaxf(rsv * ac[rt][r] + be[rt][r], 0.f);
                    lds[wv][nt * 16 + l15][rt * 16 + 4 * lg + r] = f2bf(hv);
                }
        }
        bf16x8 a2[2];
        a2[0] = *(const bf16x8*)(Wh + woff + 2048 + (size_t)l15 * 64 + lg * 8);
        a2[1] = *(const bf16x8*)(Wh + woff + 2048 + (size_t)l15 * 64 + 32 + lg * 8);
        float b2v[4];
#pragma unroll
        for (int r = 0; r < 4; ++r) {
            int s = 4 * lg + r;
            b2v[r] = (s < 12) ? b2[ek * 12 + s] : 0.f;
        }
#pragma unroll
        for (int nt = 0; nt < 4; ++nt) {
            bf16x8 b0 = *(const bf16x8*)&lds[wv][nt * 16 + l15][lg * 8];
            bf16x8 b1f = *(const bf16x8*)&lds[wv][nt * 16 + l15][32 + lg * 8];
            f32x4 ac2 = {};
            ac2 = __builtin_amdgcn_mfma_f32_16x16x32_bf16(a2[0], b0, ac2, 0, 0, 0);
            ac2 = __builtin_amdgcn_mfma_f32_16x16x32_bf16(a2[1], b1f, ac2, 0, 0, 0);
#pragma unroll
            for (int r = 0; r < 4; ++r) {
                int s = 4 * lg + r;
                if (s < 12) {
                    int n = n0 + nt * 16 + l15;
                    float val = ac2[r] + b2v[r];
                    if (head == 0)
                        bkc[((size_t)(eb * 12 + s) * 512 + n) * 2 + w] -= val;
                    else
                        acc[(size_t)(eb * 12 + s) * 512 + n] += val;
                }
            }
        }
    }
}

// ---------------------------------------------------------------------------
__global__ __launch_bounds__(256) void k_final(const float* __restrict__ acc,
                                               const float* __restrict__ ew,
                                               float* __restrict__ out) {
    int i = blockIdx.x * 256 + threadIdx.x;  // 49152
    out[i] = ew[0] * acc[i] + ew[1] * acc[49152 + i];
}

// ---------------------------------------------------------------------------
extern "C" void kernel_launch(void* const* d_in, const int* in_sizes, int n_in,
                              void* d_out, int out_size, void* d_ws, size_t ws_size,
                              hipStream_t stream) {
    const float* X    = (const float*)d_in[0];
    const float* adj  = (const float*)d_in[1];
    const float* ew   = (const float*)d_in[2];
    const float* Wst  = (const float*)d_in[3];
    const float* bst  = (const float*)d_in[4];
    const float* Wf2  = (const float*)d_in[5];
    const float* Wf3  = (const float*)d_in[6];
    const float* Wf5  = (const float*)d_in[7];
    const float* Wf7  = (const float*)d_in[8];
    const float* bf   = (const float*)d_in[9];
    const float* Wg2  = (const float*)d_in[10];
    const float* Wg3  = (const float*)d_in[11];
    const float* Wg5  = (const float*)d_in[12];
    const float* Wg7  = (const float*)d_in[13];
    const float* bg   = (const float*)d_in[14];
    const float* Wgc1 = (const float*)d_in[15];
    const float* bgc1 = (const float*)d_in[16];
    const float* Wgc2 = (const float*)d_in[17];
    const float* bgc2 = (const float*)d_in[18];
    const float* Wb1  = (const float*)d_in[19];
    const float* bb1  = (const float*)d_in[20];
    const float* Wb2  = (const float*)d_in[21];
    const float* bb2  = (const float*)d_in[22];
    const float* Wfc1 = (const float*)d_in[23];
    const float* bfc1 = (const float*)d_in[24];
    const float* Wfc2 = (const float*)d_in[25];
    const float* bfc2 = (const float*)d_in[26];

    float* ws = (float*)d_ws;
    size_t off = 0;
    auto alloc = [&](size_t nf) { float* p = ws + off; off += nf; return p; };
    float* di    = alloc(512);
    ushort_t* Anb   = (ushort_t*)alloc(512 * 512 / 2);
    ushort_t* AnTb  = (ushort_t*)alloc(512 * 512 / 2);
    ushort_t* An2b  = (ushort_t*)alloc(512 * 512 / 2);
    ushort_t* An2Tb = (ushort_t*)alloc(512 * 512 / 2);
    float* bkc   = alloc((size_t)EE * BATCH * 12 * 512 * 2);
    float* acc   = alloc((size_t)EE * BATCH * 12 * 512);
    float* stats = alloc(32);
    ushort_t* Amix = (ushort_t*)alloc(2 * 32 * 160 / 2);
    float* bsum  = alloc(64);
    ushort_t* Wb = (ushort_t*)alloc(14336);
    ushort_t* Whd = (ushort_t*)alloc(6144);
    float* rSb   = alloc(256);
    float* x     = alloc((size_t)16 * 26 * 32 * 512);
    ushort_t* xb = (ushort_t*)alloc((size_t)16 * 26 * 512 * 32 / 2);
    size_t hbuf_f = (size_t)16 * 20 * 32 * 512 / 2;  // bf16 old-layout, float units
    ushort_t* h   = (ushort_t*)alloc(hbuf_f);
    ushort_t* buf5 = (ushort_t*)alloc((size_t)16 * 20 * 512 * 160 / 2);
    if (off * sizeof(float) > ws_size) return;  // workspace too small: bail

    // Graph normalization + An^2 precompute
    k_rowsum<<<512, 256, 0, stream>>>(adj, di);
    k_norm<<<1024, 256, 0, stream>>>(adj, di, Anb, AnTb);
    k_An2<<<dim3(2, 8), 256, 0, stream>>>(Anb, AnTb, An2b, An2Tb);

    // Residual init (both experts start from X) + output accumulator zero
    hipMemcpyAsync(bkc, X, (size_t)98304 * 4, hipMemcpyDeviceToDevice, stream);
    hipMemcpyAsync(bkc + 98304, X, (size_t)98304 * 4, hipMemcpyDeviceToDevice, stream);
    hipMemsetAsync(acc, 0, (size_t)EE * BATCH * 12 * 512 * 4, stream);

    for (int kb = 0; kb < NBK; ++kb) {
        k_prep<<<116, 256, 0, stream>>>(Wf2, Wf3, Wf5, Wf7, Wg2, Wg3, Wg5, Wg7, Wb,
                                        Wgc1, bgc1, Wgc2, bgc2, Amix, bsum,
                                        Wb1, Wb2, Wfc1, Wfc2, Whd, rSb, kb);
        k_start<<<dim3(2, 26, 16), 256, 0, stream>>>(bkc, x, xb, Wst, bst, kb);
        int cur = 26;
        for (int it = 0; it < 4; ++it) {
            int L = cur - 6;
            k_incept_mfma<<<dim3(4, L, 16), 256, 0, stream>>>(
                xb, h, buf5, Wb, bf, bg, kb, cur, L);
            k_gemm4<<<dim3(2 * L, 8, 2), 256, 0, stream>>>(
                h, Anb, An2b, AnTb, An2Tb, buf5);
            k_combine_mfma<<<dim3(L, 16), 256, 0, stream>>>(x, xb, buf5, Amix, bsum, L);
            cur -= 6;
        }
        k_lnstats<<<16, 256, 0, stream>>>(x, stats);
        k_heads_mfma<<<dim3(2, 2, 16), 256, 0, stream>>>(xb, stats, bkc, acc, Whd, rSb,
                                                         bb1, bb2, bfc1, bfc2, kb);
    }
    k_final<<<192, 256, 0, stream>>>(acc, ew, (float*)d_out);
}

// Round 15
// 768.020 us; speedup vs baseline: 1.2120x; 1.0222x over previous
//
#include <hip/hip_runtime.h>
#include <stddef.h>

// Problem constants (E=2 experts, NB=2 blocks, B=8 batch, N=512 nodes)
#define EE 2
#define NBK 2
#define BATCH 8

typedef unsigned short ushort_t;
typedef short bf16x8 __attribute__((ext_vector_type(8)));
typedef float f32x4 __attribute__((ext_vector_type(4)));
typedef unsigned short u16x4 __attribute__((ext_vector_type(4)));

__device__ __forceinline__ ushort_t f2bf(float f) {
    unsigned int u = __float_as_uint(f);
    u += 0x7FFF + ((u >> 16) & 1);
    return (ushort_t)(u >> 16);
}
__device__ __forceinline__ float bf2f(ushort_t h) {
    return __uint_as_float(((unsigned int)h) << 16);
}

// ---------------------------------------------------------------------------
__global__ __launch_bounds__(256) void k_rowsum(const float* __restrict__ adj,
                                                float* __restrict__ di) {
    int v = blockIdx.x;
    int tid = threadIdx.x;
    float s = 0.f;
    for (int w = tid; w < 512; w += 256)
        s += adj[v * 512 + w] + (w == v ? 1.f : 0.f);
    for (int off = 32; off; off >>= 1) s += __shfl_down(s, off);
    __shared__ float red[4];
    if ((tid & 63) == 0) red[tid >> 6] = s;
    __syncthreads();
    if (tid == 0) {
        float t = red[0] + red[1] + red[2] + red[3];
        di[v] = rsqrtf(t);
    }
}

__global__ __launch_bounds__(256) void k_norm(const float* __restrict__ adj,
                                              const float* __restrict__ di,
                                              ushort_t* __restrict__ An,
                                              ushort_t* __restrict__ AnT) {
    int idx = blockIdx.x * 256 + threadIdx.x;  // 0..262143
    int v = idx >> 9, w = idx & 511;
    float a = adj[idx] + (v == w ? 1.f : 0.f);
    ushort_t val = f2bf(di[v] * a * di[w]);
    An[idx] = val;
    AnT[w * 512 + v] = val;
}

// ---------------------------------------------------------------------------
// An2 = An·An (row-major); An2T = (An2)^T.
__global__ __launch_bounds__(256) void k_An2(
    const ushort_t* __restrict__ Anb, const ushort_t* __restrict__ AnTb,
    ushort_t* __restrict__ An2, ushort_t* __restrict__ An2T) {
    int tid = threadIdx.x;
    int w = tid >> 6, lane = tid & 63;
    int l15 = lane & 15, lg = lane >> 4;
    int wbase = blockIdx.x * 256 + w * 64;
    int n0 = blockIdx.y * 64;
    f32x4 acc[4][4] = {};
    const ushort_t* Ap = Anb + (size_t)(wbase + l15) * 512 + lg * 8;
    const ushort_t* Bp = AnTb + (size_t)(n0 + l15) * 512 + lg * 8;
    bf16x8 avC[4], bvC[4], avN[4], bvN[4];
#pragma unroll
    for (int i = 0; i < 4; ++i) {
        avC[i] = *(const bf16x8*)(Ap + (size_t)i * 16 * 512);
        bvC[i] = *(const bf16x8*)(Bp + (size_t)i * 16 * 512);
    }
#pragma unroll 2
    for (int k0 = 0; k0 < 512; k0 += 32) {
        int kn = k0 + 32;
        if (kn < 512) {
#pragma unroll
            for (int i = 0; i < 4; ++i) {
                avN[i] = *(const bf16x8*)(Ap + (size_t)i * 16 * 512 + kn);
                bvN[i] = *(const bf16x8*)(Bp + (size_t)i * 16 * 512 + kn);
            }
        }
#pragma unroll
        for (int mf = 0; mf < 4; ++mf)
#pragma unroll
            for (int nf = 0; nf < 4; ++nf)
                acc[mf][nf] = __builtin_amdgcn_mfma_f32_16x16x32_bf16(
                    avC[mf], bvC[nf], acc[mf][nf], 0, 0, 0);
#pragma unroll
        for (int i = 0; i < 4; ++i) { avC[i] = avN[i]; bvC[i] = bvN[i]; }
    }
#pragma unroll
    for (int mf = 0; mf < 4; ++mf)
#pragma unroll
        for (int nf = 0; nf < 4; ++nf) {
            int col = n0 + 16 * nf + l15;
            int row0 = wbase + 16 * mf + 4 * lg;
            u16x4 q;
#pragma unroll
            for (int r = 0; r < 4; ++r) {
                ushort_t vb = f2bf(acc[mf][nf][r]);
                q[r] = vb;
                An2[(size_t)(row0 + r) * 512 + col] = vb;
            }
            *(u16x4*)(An2T + (size_t)col * 512 + row0) = q;
        }
}

// ---------------------------------------------------------------------------
// Fused per-kb weight prep: blocks 0..111 -> inception Weff; 112,113 ->
// mix matrices (e = bx-112); 114,115 -> head weights (e = bx-114).
__global__ __launch_bounds__(256) void k_prep(
    const float* __restrict__ Wf2, const float* __restrict__ Wf3,
    const float* __restrict__ Wf5, const float* __restrict__ Wf7,
    const float* __restrict__ Wg2, const float* __restrict__ Wg3,
    const float* __restrict__ Wg5, const float* __restrict__ Wg7,
    ushort_t* __restrict__ Wb,
    const float* __restrict__ Wgc1, const float* __restrict__ bgc1,
    const float* __restrict__ Wgc2, const float* __restrict__ bgc2,
    ushort_t* __restrict__ Amix, float* __restrict__ bsum,
    const float* __restrict__ Wb1, const float* __restrict__ Wb2,
    const float* __restrict__ Wfc1, const float* __restrict__ Wfc2,
    ushort_t* __restrict__ Whd, float* __restrict__ rS, int kb) {
    int bx = blockIdx.x;
    if (bx < 112) {
        int idx = bx * 256 + threadIdx.x;  // 28672 total
        if (idx >= 2 * 2 * 7 * 2 * 16 * 32) return;
        int c = idx & 31;
        int t1 = idx >> 5;
        int o16 = t1 & 15;
        int t2 = t1 >> 4;
        int ot = t2 & 1;
        int t3 = t2 >> 1;
        int dt = t3 % 7;
        int t4 = t3 / 7;
        int fg = t4 & 1;
        int e = t4 >> 1;
        int ek = e * NBK + kb;
        int o = ot * 16 + o16;
        int grp = o >> 3, oo = o & 7;
        const int kstab[4] = {2, 3, 5, 7};
        int ks = kstab[grp];
        int lo = 7 - ks;
        float val = 0.f;
        if (dt >= lo) {
            int di = dt - lo;
            const float* W;
            if (grp == 0) W = (fg ? Wg2 : Wf2) + (size_t)ek * 512 + oo * 64 + c * 2 + di;
            else if (grp == 1) W = (fg ? Wg3 : Wf3) + (size_t)ek * 768 + oo * 96 + c * 3 + di;
            else if (grp == 2) W = (fg ? Wg5 : Wf5) + (size_t)ek * 1280 + oo * 160 + c * 5 + di;
            else W = (fg ? Wg7 : Wf7) + (size_t)ek * 1792 + oo * 224 + c * 7 + di;
            val = *W;
        }
        Wb[idx] = f2bf(val);
    } else if (bx < 114) {
        int e = bx - 112;
        int ek = e * NBK + kb;
        const float* W1 = Wgc1 + (size_t)ek * 32 * 96;
        const float* W2 = Wgc2 + (size_t)ek * 32 * 96;
        for (int idx = threadIdx.x; idx < 32 * 160; idx += 256) {
            int co = idx / 160, k = idx % 160;
            int slot = k >> 5, cp = k & 31;
            float val;
            if (slot == 0)
                val = W1[co * 96 + cp] + W1[co * 96 + 32 + cp] + W1[co * 96 + 64 + cp] +
                      W2[co * 96 + cp] + W2[co * 96 + 32 + cp] + W2[co * 96 + 64 + cp];
            else if (slot == 1) val = 0.5f * W1[co * 96 + 32 + cp] + W1[co * 96 + 64 + cp];
            else if (slot == 2) val = 0.25f * W1[co * 96 + 64 + cp];
            else if (slot == 3) val = 0.5f * W2[co * 96 + 32 + cp] + W2[co * 96 + 64 + cp];
            else val = 0.25f * W2[co * 96 + 64 + cp];
            Amix[((size_t)e * 32 + co) * 160 + k] = f2bf(val);
        }
        if (threadIdx.x < 32)
            bsum[e * 32 + threadIdx.x] =
                bgc1[ek * 32 + threadIdx.x] + bgc2[ek * 32 + threadIdx.x];
    } else {
        int e = bx - 114;
        int ek = e * NBK + kb;
        ushort_t* Wh = Whd + (size_t)e * 6144;
        for (int i = threadIdx.x; i < 2048; i += 256)
            Wh[i] = f2bf(Wb1[(size_t)ek * 2048 + i]);
        for (int i = threadIdx.x; i < 1024; i += 256) {
            int r = i >> 6, d = i & 63;
            Wh[2048 + i] = f2bf(r < 12 ? Wb2[(size_t)ek * 768 + r * 64 + d] : 0.f);
        }
        for (int i = threadIdx.x; i < 2048; i += 256)
            Wh[3072 + i] = f2bf(Wfc1[(size_t)ek * 2048 + i]);
        for (int i = threadIdx.x; i < 1024; i += 256) {
            int r = i >> 6, d = i & 63;
            Wh[5120 + i] = f2bf(r < 12 ? Wfc2[(size_t)ek * 768 + r * 64 + d] : 0.f);
        }
        if (threadIdx.x < 64) {
            int d = threadIdx.x;
            float s1 = 0.f, s2 = 0.f;
            for (int c = 0; c < 32; ++c) {
                s1 += Wb1[(size_t)ek * 2048 + d * 32 + c];
                s2 += Wfc1[(size_t)ek * 2048 + d * 32 + c];
            }
            rS[e * 128 + d] = s1;
            rS[e * 128 + 64 + d] = s2;
        }
    }
}

// ---------------------------------------------------------------------------
// start: writes x fp32 [eb][t][c][n] and bf16 mirror xb [eb][t][n][c]
__global__ __launch_bounds__(256) void k_start(const float* __restrict__ bkc,
                                               float* __restrict__ x,
                                               ushort_t* __restrict__ xb,
                                               const float* __restrict__ Wst,
                                               const float* __restrict__ bst,
                                               int kb) {
    int n = blockIdx.x * 256 + threadIdx.x;
    int t = blockIdx.y;
    int eb = blockIdx.z;
    int e = eb >> 3;
    int ek = e * NBK + kb;
    const float* Wp = Wst + (size_t)ek * 32 * 2;
    const float* bp = bst + (size_t)ek * 32;
    float in0 = 0.f, in1 = 0.f;
    if (t >= 14) {
        const float* p = bkc + ((size_t)(eb * 12 + (t - 14)) * 512 + n) * 2;
        in0 = p[0];
        in1 = p[1];
    }
    float* xo = x + ((size_t)(eb * 26 + t) * 32) * 512 + n;
    ushort_t tmp[32];
#pragma unroll
    for (int c = 0; c < 32; ++c) {
        float v = bp[c] + Wp[c * 2] * in0 + Wp[c * 2 + 1] * in1;
        xo[(size_t)c * 512] = v;
        tmp[c] = f2bf(v);
    }
    ushort_t* xbp = xb + ((size_t)(eb * 26 + t) * 512 + n) * 32;
#pragma unroll
    for (int q = 0; q < 4; ++q)
        *(bf16x8*)(xbp + q * 8) = *(bf16x8*)(tmp + q * 8);
}

// ---------------------------------------------------------------------------
// MFMA inception: writes h_old [col][n] (GEMM A operand) + buf5 slot0 (Y)
__global__ __launch_bounds__(256) void k_incept_mfma(
    const ushort_t* __restrict__ xb, ushort_t* __restrict__ h,
    ushort_t* __restrict__ buf5, const ushort_t* __restrict__ Wb,
    const float* __restrict__ bf, const float* __restrict__ bg,
    int kb, int cur_len, int L) {
    int j = blockIdx.y, eb = blockIdx.z, e = eb >> 3, ek = e * NBK + kb;
    int tid = threadIdx.x;
    int w = tid >> 6, lane = tid & 63;
    int l15 = lane & 15, lg = lane >> 4;
    int ot = w >> 1;
    int n0base = blockIdx.x * 128 + (w & 1) * 64;
    int t0 = 26 - cur_len + j;

    const ushort_t* WbE = Wb + (size_t)e * 14336;
    bf16x8 af_[7], ag_[7];
#pragma unroll
    for (int dt = 0; dt < 7; ++dt) {
        af_[dt] = *(const bf16x8*)(WbE + ((size_t)(dt * 2 + ot) * 16 + l15) * 32 + lg * 8);
        ag_[dt] = *(const bf16x8*)(WbE + 7168 + ((size_t)(dt * 2 + ot) * 16 + l15) * 32 + lg * 8);
    }
    float bfv[4], bgv[4];
#pragma unroll
    for (int r = 0; r < 4; ++r) {
        int o = ot * 16 + 4 * lg + r;
        bfv[r] = bf[ek * 32 + o];
        bgv[r] = bg[ek * 32 + o];
    }
    size_t colbase = ((size_t)eb * L + j) * 32;
    size_t rowb = ((size_t)eb * L + j) * 512;
    const ushort_t* xe = xb + ((size_t)eb * 26) * 512 * 32;
#pragma unroll
    for (int nt = 0; nt < 4; ++nt) {
        int n0 = n0base + nt * 16;
        // batch all 7 window loads up-front (ILP), then run the MFMA chain
        bf16x8 bfr[7];
#pragma unroll
        for (int dt = 0; dt < 7; ++dt)
            bfr[dt] = *(const bf16x8*)(xe + ((size_t)(t0 + dt) * 512 + n0 + l15) * 32 + lg * 8);
        f32x4 accf = {}, accg = {};
#pragma unroll
        for (int dt = 0; dt < 7; ++dt) {
            accf = __builtin_amdgcn_mfma_f32_16x16x32_bf16(af_[dt], bfr[dt], accf, 0, 0, 0);
            accg = __builtin_amdgcn_mfma_f32_16x16x32_bf16(ag_[dt], bfr[dt], accg, 0, 0, 0);
        }
        u16x4 q;
#pragma unroll
        for (int r = 0; r < 4; ++r) {
            float a = accf[r] + bfv[r];
            float b = accg[r] + bgv[r];
            float hv = tanhf(a) * (1.f / (1.f + expf(-b)));
            ushort_t hb = f2bf(hv);
            q[r] = hb;
            int o = ot * 16 + 4 * lg + r;
            h[(colbase + o) * 512 + n0 + l15] = hb;
        }
        *(u16x4*)(buf5 + (rowb + n0 + l15) * 160 + ot * 16 + 4 * lg) = q;
    }
}

// ---------------------------------------------------------------------------
// 4-way NT GEMM from h with LDS-staged B tile, BK=64 (8 barriers).
// slot z+1 of buf5 = h @ Bz^T; z: 0->An, 1->An2, 2->AnT, 3->An2T
// Block = 4 waves x 64 rows = 256 rows, 64 cols. Per K-step: 8 batched A
// global loads + 8 LDS B reads feed 32 MFMAs. B chunk (64 cols x 64 K =
// 8 KB) staged cooperatively double-buffered: thread t loads 2x16B
// (col=t>>2, kq=(t&3)*8 and +32).
__global__ __launch_bounds__(256) void k_gemm4(
    const ushort_t* __restrict__ A,
    const ushort_t* __restrict__ B0, const ushort_t* __restrict__ B1,
    const ushort_t* __restrict__ B2, const ushort_t* __restrict__ B3,
    ushort_t* __restrict__ buf5) {
    __shared__ __align__(16) ushort_t Bs[2][64][72];
    int z = blockIdx.z;
    const ushort_t* B = (z == 0) ? B0 : (z == 1) ? B1 : (z == 2) ? B2 : B3;
    int slot = z + 1;
    int tid = threadIdx.x;
    int w = tid >> 6, lane = tid & 63;
    int l15 = lane & 15, lg = lane >> 4;
    int wbase = blockIdx.x * 256 + w * 64;
    int n0 = blockIdx.y * 64;
    int scol = tid >> 2;          // 0..63
    int skq = (tid & 3) * 8;      // 0,8,16,24
    const ushort_t* Bsrc = B + (size_t)(n0 + scol) * 512 + skq;
    const ushort_t* Ap = A + (size_t)(wbase + l15) * 512 + lg * 8;
    f32x4 acc[4][4] = {};
    bf16x8 bregN0, bregN1;
    {   // stage chunk 0 (64 K), prefetch chunk 1 into regs
        *(bf16x8*)&Bs[0][scol][skq] = *(const bf16x8*)(Bsrc);
        *(bf16x8*)&Bs[0][scol][skq + 32] = *(const bf16x8*)(Bsrc + 32);
        bregN0 = *(const bf16x8*)(Bsrc + 64);
        bregN1 = *(const bf16x8*)(Bsrc + 96);
    }
    __syncthreads();
#pragma unroll
    for (int ks = 0; ks < 8; ++ks) {
        int cur = ks & 1;
        int k0 = ks * 64;
        bf16x8 av[4][2], bv[4][2];
#pragma unroll
        for (int mf = 0; mf < 4; ++mf)
#pragma unroll
            for (int kk = 0; kk < 2; ++kk)
                av[mf][kk] = *(const bf16x8*)(Ap + (size_t)mf * 16 * 512 + k0 + kk * 32);
#pragma unroll
        for (int nf = 0; nf < 4; ++nf)
#pragma unroll
            for (int kk = 0; kk < 2; ++kk)
                bv[nf][kk] = *(const bf16x8*)&Bs[cur][16 * nf + l15][kk * 32 + lg * 8];
        if (ks < 7) {   // write chunk ks+1
            *(bf16x8*)&Bs[cur ^ 1][scol][skq] = bregN0;
            *(bf16x8*)&Bs[cur ^ 1][scol][skq + 32] = bregN1;
        }
        if (ks < 6) {   // prefetch chunk ks+2
            bregN0 = *(const bf16x8*)(Bsrc + (ks + 2) * 64);
            bregN1 = *(const bf16x8*)(Bsrc + (ks + 2) * 64 + 32);
        }
#pragma unroll
        for (int kk = 0; kk < 2; ++kk)
#pragma unroll
            for (int mf = 0; mf < 4; ++mf)
#pragma unroll
                for (int nf = 0; nf < 4; ++nf)
                    acc[mf][nf] = __builtin_amdgcn_mfma_f32_16x16x32_bf16(
                        av[mf][kk], bv[nf][kk], acc[mf][nf], 0, 0, 0);
        __syncthreads();
    }
#pragma unroll
    for (int mf = 0; mf < 4; ++mf) {
        int jeb = (wbase >> 5) + (mf >> 1);
        int c0 = 16 * (mf & 1) + 4 * lg;
#pragma unroll
        for (int nf = 0; nf < 4; ++nf) {
            int col = n0 + 16 * nf + l15;
            u16x4 q;
#pragma unroll
            for (int r = 0; r < 4; ++r) q[r] = f2bf(acc[mf][nf][r]);
            *(u16x4*)(buf5 + ((size_t)jeb * 512 + col) * 160 + slot * 32 + c0) = q;
        }
    }
}

// ---------------------------------------------------------------------------
// MFMA combine: g = Amix @ buf5^T + bsum; x -= 0.25*g; xb = bf16(x)
__global__ __launch_bounds__(256) void k_combine_mfma(
    float* __restrict__ x, ushort_t* __restrict__ xb,
    const ushort_t* __restrict__ buf5, const ushort_t* __restrict__ Amix,
    const float* __restrict__ bsum, int L) {
    int j = blockIdx.x, eb = blockIdx.y, e = eb >> 3;
    int tid = threadIdx.x, wv = tid >> 6, lane = tid & 63;
    int l15 = lane & 15, lg = lane >> 4;
    int t = 26 - L + j;
    const ushort_t* Ae = Amix + (size_t)e * 32 * 160;
    bf16x8 a[2][5];
#pragma unroll
    for (int ct = 0; ct < 2; ++ct)
#pragma unroll
        for (int ks = 0; ks < 5; ++ks)
            a[ct][ks] = *(const bf16x8*)(Ae + (size_t)(ct * 16 + l15) * 160 + ks * 32 + lg * 8);
    float bs[2][4];
#pragma unroll
    for (int ct = 0; ct < 2; ++ct)
#pragma unroll
        for (int r = 0; r < 4; ++r) bs[ct][r] = bsum[e * 32 + ct * 16 + 4 * lg + r];
    size_t rowb = ((size_t)eb * L + j) * 512;
    size_t xtb = ((size_t)(eb * 26 + t) * 32) * 512;
    ushort_t* xbt = xb + ((size_t)(eb * 26 + t) * 512) * 32;
#pragma unroll
    for (int nt = 0; nt < 8; ++nt) {
        int n = wv * 128 + nt * 16 + l15;
        const ushort_t* bp = buf5 + (rowb + n) * 160 + lg * 8;
        bf16x8 b[5];
#pragma unroll
        for (int ks = 0; ks < 5; ++ks) b[ks] = *(const bf16x8*)(bp + ks * 32);
        f32x4 acc[2] = {};
#pragma unroll
        for (int ks = 0; ks < 5; ++ks) {
            acc[0] = __builtin_amdgcn_mfma_f32_16x16x32_bf16(a[0][ks], b[ks], acc[0], 0, 0, 0);
            acc[1] = __builtin_amdgcn_mfma_f32_16x16x32_bf16(a[1][ks], b[ks], acc[1], 0, 0, 0);
        }
#pragma unroll
        for (int ct = 0; ct < 2; ++ct) {
            u16x4 q;
#pragma unroll
            for (int r = 0; r < 4; ++r) {
                int co = ct * 16 + 4 * lg + r;
                float* xp = x + xtb + (size_t)co * 512 + n;
                float nv = *xp - 0.25f * (acc[ct][r] + bs[ct][r]);
                *xp = nv;
                q[r] = f2bf(nv);
            }
            *(u16x4*)(xbt + (size_t)n * 32 + ct * 16 + 4 * lg) = q;
        }
    }
}

// ---------------------------------------------------------------------------
__global__ __launch_bounds__(256) void k_lnstats(const float* __restrict__ x,
                                                 float* __restrict__ stats) {
    int eb = blockIdx.x;
    const float* p = x + ((size_t)(eb * 26 + 24) * 32) * 512;
    float s = 0.f, s2 = 0.f;
    for (int i = threadIdx.x; i < 32768; i += 256) {
        float v = p[i];
        s += v;
        s2 += v * v;
    }
    for (int off = 32; off; off >>= 1) {
        s += __shfl_down(s, off);
        s2 += __shfl_down(s2, off);
    }
    __shared__ float r1[4], r2[4];
    if ((threadIdx.x & 63) == 0) {
        r1[threadIdx.x >> 6] = s;
        r2[threadIdx.x >> 6] = s2;
    }
    __syncthreads();
    if (threadIdx.x == 0) {
        float S = r1[0] + r1[1] + r1[2] + r1[3];
        float S2 = r2[0] + r2[1] + r2[2] + r2[3];
        float mu = S / 32768.f;
        float var = S2 / 32768.f - mu * mu;
        stats[eb * 2] = mu;
        stats[eb * 2 + 1] = rsqrtf(var + 1e-5f);
    }
}

// ---------------------------------------------------------------------------
__global__ __launch_bounds__(256) void k_heads_mfma(
    const ushort_t* __restrict__ xb, const float* __restrict__ stats,
    float* __restrict__ bkc, float* __restrict__ acc,
    const ushort_t* __restrict__ Whd, const float* __restrict__ rS,
    const float* __restrict__ bb1, const float* __restrict__ bb2,
    const float* __restrict__ bfc1, const float* __restrict__ bfc2,
    int kb) {
    __shared__ __align__(16) ushort_t lds[4][64][72];
    int w = blockIdx.y, eb = blockIdx.z;
    int e = eb >> 3, ek = e * NBK + kb;
    int tid = threadIdx.x, wv = tid >> 6, lane = tid & 63;
    int l15 = lane & 15, lg = lane >> 4;
    int n0 = blockIdx.x * 256 + wv * 64;
    float mu = stats[eb * 2], rsv = stats[eb * 2 + 1];
    const ushort_t* Wh = Whd + (size_t)e * 6144;
    const ushort_t* xrow = xb + ((size_t)(eb * 26 + 24 + w) * 512) * 32;

#pragma unroll
    for (int head = 0; head < 2; ++head) {
        if (head == 1 && w == 0) break;  // fc only for w==1
        int woff = head ? 3072 : 0;
        const float* b1 = head ? bfc1 : bb1;
        const float* b2 = head ? bfc2 : bb2;
        const float* rs1 = rS + e * 128 + (head ? 64 : 0);
        bf16x8 a1[4];
#pragma unroll
        for (int rt = 0; rt < 4; ++rt)
            a1[rt] = *(const bf16x8*)(Wh + woff + (size_t)(rt * 16 + l15) * 32 + lg * 8);
        float be[4][4];
#pragma unroll
        for (int rt = 0; rt < 4; ++rt)
#pragma unroll
            for (int r = 0; r < 4; ++r) {
                int d = rt * 16 + 4 * lg + r;
                be[rt][r] = b1[ek * 64 + d] - rsv * mu * rs1[d];
            }
#pragma unroll
        for (int nt = 0; nt < 4; ++nt) {
            bf16x8 bv = *(const bf16x8*)(xrow + (size_t)(n0 + nt * 16 + l15) * 32 + lg * 8);
            f32x4 ac[4] = {};
#pragma unroll
            for (int rt = 0; rt < 4; ++rt)
                ac[rt] = __builtin_amdgcn_mfma_f32_16x16x32_bf16(a1[rt], bv, ac[rt], 0, 0, 0);
#pragma unroll
            for (int rt = 0; rt < 4; ++rt)
#pragma unroll
                for (int r = 0; r < 4; ++r) {
                    float hv = fmaxf(rsv * ac[rt][r] + be[rt][r], 0.f);
                    lds[wv][nt * 16 + l15][rt * 16 + 4 * lg + r] = f2bf(hv);
                }
        }
        bf16x8 a2[2];
        a2[0] = *(const bf16x8*)(Wh + woff + 2048 + (size_t)l15 * 64 + lg * 8);
        a2[1] = *(const bf16x8*)(Wh + woff + 2048 + (size_t)l15 * 64 + 32 + lg * 8);
        float b2v[4];
#pragma unroll
        for (int r = 0; r < 4; ++r) {
            int s = 4 * lg + r;
            b2v[r] = (s < 12) ? b2[ek * 12 + s] : 0.f;
        }
#pragma unroll
        for (int nt = 0; nt < 4; ++nt) {
            bf16x8 b0 = *(const bf16x8*)&lds[wv][nt * 16 + l15][lg * 8];
            bf16x8 b1f = *(const bf16x8*)&lds[wv][nt * 16 + l15][32 + lg * 8];
            f32x4 ac2 = {};
            ac2 = __builtin_amdgcn_mfma_f32_16x16x32_bf16(a2[0], b0, ac2, 0, 0, 0);
            ac2 = __builtin_amdgcn_mfma_f32_16x16x32_bf16(a2[1], b1f, ac2, 0, 0, 0);
#pragma unroll
            for (int r = 0; r < 4; ++r) {
                int s = 4 * lg + r;
                if (s < 12) {
                    int n = n0 + nt * 16 + l15;
                    float val = ac2[r] + b2v[r];
                    if (head == 0)
                        bkc[((size_t)(eb * 12 + s) * 512 + n) * 2 + w] -= val;
                    else
                        acc[(size_t)(eb * 12 + s) * 512 + n] += val;
                }
            }
        }
    }
}

// ---------------------------------------------------------------------------
__global__ __launch_bounds__(256) void k_final(const float* __restrict__ acc,
                                               const float* __restrict__ ew,
                                               float* __restrict__ out) {
    int i = blockIdx.x * 256 + threadIdx.x;  // 49152
    out[i] = ew[0] * acc[i] + ew[1] * acc[49152 + i];
}

// ---------------------------------------------------------------------------
extern "C" void kernel_launch(void* const* d_in, const int* in_sizes, int n_in,
                              void* d_out, int out_size, void* d_ws, size_t ws_size,
                              hipStream_t stream) {
    const float* X    = (const float*)d_in[0];
    const float* adj  = (const float*)d_in[1];
    const float* ew   = (const float*)d_in[2];
    const float* Wst  = (const float*)d_in[3];
    const float* bst  = (const float*)d_in[4];
    const float* Wf2  = (const float*)d_in[5];
    const float* Wf3  = (const float*)d_in[6];
    const float* Wf5  = (const float*)d_in[7];
    const float* Wf7  = (const float*)d_in[8];
    const float* bf   = (const float*)d_in[9];
    const float* Wg2  = (const float*)d_in[10];
    const float* Wg3  = (const float*)d_in[11];
    const float* Wg5  = (const float*)d_in[12];
    const float* Wg7  = (const float*)d_in[13];
    const float* bg   = (const float*)d_in[14];
    const float* Wgc1 = (const float*)d_in[15];
    const float* bgc1 = (const float*)d_in[16];
    const float* Wgc2 = (const float*)d_in[17];
    const float* bgc2 = (const float*)d_in[18];
    const float* Wb1  = (const float*)d_in[19];
    const float* bb1  = (const float*)d_in[20];
    const float* Wb2  = (const float*)d_in[21];
    const float* bb2  = (const float*)d_in[22];
    const float* Wfc1 = (const float*)d_in[23];
    const float* bfc1 = (const float*)d_in[24];
    const float* Wfc2 = (const float*)d_in[25];
    const float* bfc2 = (const float*)d_in[26];

    float* ws = (float*)d_ws;
    size_t off = 0;
    auto alloc = [&](size_t nf) { float* p = ws + off; off += nf; return p; };
    float* di    = alloc(512);
    ushort_t* Anb   = (ushort_t*)alloc(512 * 512 / 2);
    ushort_t* AnTb  = (ushort_t*)alloc(512 * 512 / 2);
    ushort_t* An2b  = (ushort_t*)alloc(512 * 512 / 2);
    ushort_t* An2Tb = (ushort_t*)alloc(512 * 512 / 2);
    float* bkc   = alloc((size_t)EE * BATCH * 12 * 512 * 2);
    float* acc   = alloc((size_t)EE * BATCH * 12 * 512);
    float* stats = alloc(32);
    ushort_t* Amix = (ushort_t*)alloc(2 * 32 * 160 / 2);
    float* bsum  = alloc(64);
    ushort_t* Wb = (ushort_t*)alloc(14336);
    ushort_t* Whd = (ushort_t*)alloc(6144);
    float* rSb   = alloc(256);
    float* x     = alloc((size_t)16 * 26 * 32 * 512);
    ushort_t* xb = (ushort_t*)alloc((size_t)16 * 26 * 512 * 32 / 2);
    size_t hbuf_f = (size_t)16 * 20 * 32 * 512 / 2;  // bf16 old-layout, float units
    ushort_t* h   = (ushort_t*)alloc(hbuf_f);
    ushort_t* buf5 = (ushort_t*)alloc((size_t)16 * 20 * 512 * 160 / 2);
    if (off * sizeof(float) > ws_size) return;  // workspace too small: bail

    // Graph normalization + An^2 precompute
    k_rowsum<<<512, 256, 0, stream>>>(adj, di);
    k_norm<<<1024, 256, 0, stream>>>(adj, di, Anb, AnTb);
    k_An2<<<dim3(2, 8), 256, 0, stream>>>(Anb, AnTb, An2b, An2Tb);

    // Residual init (both experts start from X) + output accumulator zero
    hipMemcpyAsync(bkc, X, (size_t)98304 * 4, hipMemcpyDeviceToDevice, stream);
    hipMemcpyAsync(bkc + 98304, X, (size_t)98304 * 4, hipMemcpyDeviceToDevice, stream);
    hipMemsetAsync(acc, 0, (size_t)EE * BATCH * 12 * 512 * 4, stream);

    for (int kb = 0; kb < NBK; ++kb) {
        k_prep<<<116, 256, 0, stream>>>(Wf2, Wf3, Wf5, Wf7, Wg2, Wg3, Wg5, Wg7, Wb,
                                        Wgc1, bgc1, Wgc2, bgc2, Amix, bsum,
                                        Wb1, Wb2, Wfc1, Wfc2, Whd, rSb, kb);
        k_start<<<dim3(2, 26, 16), 256, 0, stream>>>(bkc, x, xb, Wst, bst, kb);
        int cur = 26;
        for (int it = 0; it < 4; ++it) {
            int L = cur - 6;
            k_incept_mfma<<<dim3(4, L, 16), 256, 0, stream>>>(
                xb, h, buf5, Wb, bf, bg, kb, cur, L);
            k_gemm4<<<dim3(2 * L, 8, 4), 256, 0, stream>>>(
                h, Anb, An2b, AnTb, An2Tb, buf5);
            k_combine_mfma<<<dim3(L, 16), 256, 0, stream>>>(x, xb, buf5, Amix, bsum, L);
            cur -= 6;
        }
        k_lnstats<<<16, 256, 0, stream>>>(x, stats);
        k_heads_mfma<<<dim3(2, 2, 16), 256, 0, stream>>>(xb, stats, bkc, acc, Whd, rSb,
                                                         bb1, bb2, bfc1, bfc2, kb);
    }
    k_final<<<192, 256, 0, stream>>>(acc, ew, (float*)d_out);
}

// Round 16
// 632.152 us; speedup vs baseline: 1.4725x; 1.2149x over previous
//
#include <hip/hip_runtime.h>
#include <stddef.h>

// Problem constants (E=2 experts, NB=2 blocks, B=8 batch, N=512 nodes)
#define EE 2
#define NBK 2
#define BATCH 8

typedef unsigned short ushort_t;
typedef short bf16x8 __attribute__((ext_vector_type(8)));
typedef float f32x4 __attribute__((ext_vector_type(4)));
typedef unsigned short u16x4 __attribute__((ext_vector_type(4)));

__device__ __forceinline__ ushort_t f2bf(float f) {
    unsigned int u = __float_as_uint(f);
    u += 0x7FFF + ((u >> 16) & 1);
    return (ushort_t)(u >> 16);
}
__device__ __forceinline__ float bf2f(ushort_t h) {
    return __uint_as_float(((unsigned int)h) << 16);
}

// ---------------------------------------------------------------------------
__global__ __launch_bounds__(256) void k_rowsum(const float* __restrict__ adj,
                                                float* __restrict__ di) {
    int v = blockIdx.x;
    int tid = threadIdx.x;
    float s = 0.f;
    for (int w = tid; w < 512; w += 256)
        s += adj[v * 512 + w] + (w == v ? 1.f : 0.f);
    for (int off = 32; off; off >>= 1) s += __shfl_down(s, off);
    __shared__ float red[4];
    if ((tid & 63) == 0) red[tid >> 6] = s;
    __syncthreads();
    if (tid == 0) {
        float t = red[0] + red[1] + red[2] + red[3];
        di[v] = rsqrtf(t);
    }
}

__global__ __launch_bounds__(256) void k_norm(const float* __restrict__ adj,
                                              const float* __restrict__ di,
                                              ushort_t* __restrict__ An,
                                              ushort_t* __restrict__ AnT) {
    int idx = blockIdx.x * 256 + threadIdx.x;  // 0..262143
    int v = idx >> 9, w = idx & 511;
    float a = adj[idx] + (v == w ? 1.f : 0.f);
    ushort_t val = f2bf(di[v] * a * di[w]);
    An[idx] = val;
    AnT[w * 512 + v] = val;
}

// ---------------------------------------------------------------------------
// An2 = An·An (row-major); An2T = (An2)^T.
__global__ __launch_bounds__(256) void k_An2(
    const ushort_t* __restrict__ Anb, const ushort_t* __restrict__ AnTb,
    ushort_t* __restrict__ An2, ushort_t* __restrict__ An2T) {
    int tid = threadIdx.x;
    int w = tid >> 6, lane = tid & 63;
    int l15 = lane & 15, lg = lane >> 4;
    int wbase = blockIdx.x * 256 + w * 64;
    int n0 = blockIdx.y * 64;
    f32x4 acc[4][4] = {};
    const ushort_t* Ap = Anb + (size_t)(wbase + l15) * 512 + lg * 8;
    const ushort_t* Bp = AnTb + (size_t)(n0 + l15) * 512 + lg * 8;
    bf16x8 avC[4], bvC[4], avN[4], bvN[4];
#pragma unroll
    for (int i = 0; i < 4; ++i) {
        avC[i] = *(const bf16x8*)(Ap + (size_t)i * 16 * 512);
        bvC[i] = *(const bf16x8*)(Bp + (size_t)i * 16 * 512);
    }
#pragma unroll 2
    for (int k0 = 0; k0 < 512; k0 += 32) {
        int kn = k0 + 32;
        if (kn < 512) {
#pragma unroll
            for (int i = 0; i < 4; ++i) {
                avN[i] = *(const bf16x8*)(Ap + (size_t)i * 16 * 512 + kn);
                bvN[i] = *(const bf16x8*)(Bp + (size_t)i * 16 * 512 + kn);
            }
        }
#pragma unroll
        for (int mf = 0; mf < 4; ++mf)
#pragma unroll
            for (int nf = 0; nf < 4; ++nf)
                acc[mf][nf] = __builtin_amdgcn_mfma_f32_16x16x32_bf16(
                    avC[mf], bvC[nf], acc[mf][nf], 0, 0, 0);
#pragma unroll
        for (int i = 0; i < 4; ++i) { avC[i] = avN[i]; bvC[i] = bvN[i]; }
    }
#pragma unroll
    for (int mf = 0; mf < 4; ++mf)
#pragma unroll
        for (int nf = 0; nf < 4; ++nf) {
            int col = n0 + 16 * nf + l15;
            int row0 = wbase + 16 * mf + 4 * lg;
            u16x4 q;
#pragma unroll
            for (int r = 0; r < 4; ++r) {
                ushort_t vb = f2bf(acc[mf][nf][r]);
                q[r] = vb;
                An2[(size_t)(row0 + r) * 512 + col] = vb;
            }
            *(u16x4*)(An2T + (size_t)col * 512 + row0) = q;
        }
}

// ---------------------------------------------------------------------------
// Fused weight prep for BOTH kb: grid 232; bx<116 -> kb=0, else kb=1.
// Within a kb-half: 0..111 inception Weff; 112,113 mix; 114,115 heads.
__global__ __launch_bounds__(256) void k_prep(
    const float* __restrict__ Wf2, const float* __restrict__ Wf3,
    const float* __restrict__ Wf5, const float* __restrict__ Wf7,
    const float* __restrict__ Wg2, const float* __restrict__ Wg3,
    const float* __restrict__ Wg5, const float* __restrict__ Wg7,
    ushort_t* __restrict__ Wb,
    const float* __restrict__ Wgc1, const float* __restrict__ bgc1,
    const float* __restrict__ Wgc2, const float* __restrict__ bgc2,
    ushort_t* __restrict__ Amix, float* __restrict__ bsum,
    const float* __restrict__ Wb1, const float* __restrict__ Wb2,
    const float* __restrict__ Wfc1, const float* __restrict__ Wfc2,
    ushort_t* __restrict__ Whd, float* __restrict__ rS) {
    int bx = blockIdx.x;
    int kb = bx >= 116 ? 1 : 0;
    bx -= kb * 116;
    ushort_t* Wb_k = Wb + (size_t)kb * 28672;
    ushort_t* Amix_k = Amix + (size_t)kb * 10240;
    float* bsum_k = bsum + kb * 64;
    ushort_t* Whd_k = Whd + (size_t)kb * 12288;
    float* rS_k = rS + kb * 256;
    if (bx < 112) {
        int idx = bx * 256 + threadIdx.x;  // 28672 total
        if (idx >= 2 * 2 * 7 * 2 * 16 * 32) return;
        int c = idx & 31;
        int t1 = idx >> 5;
        int o16 = t1 & 15;
        int t2 = t1 >> 4;
        int ot = t2 & 1;
        int t3 = t2 >> 1;
        int dt = t3 % 7;
        int t4 = t3 / 7;
        int fg = t4 & 1;
        int e = t4 >> 1;
        int ek = e * NBK + kb;
        int o = ot * 16 + o16;
        int grp = o >> 3, oo = o & 7;
        const int kstab[4] = {2, 3, 5, 7};
        int ks = kstab[grp];
        int lo = 7 - ks;
        float val = 0.f;
        if (dt >= lo) {
            int di = dt - lo;
            const float* W;
            if (grp == 0) W = (fg ? Wg2 : Wf2) + (size_t)ek * 512 + oo * 64 + c * 2 + di;
            else if (grp == 1) W = (fg ? Wg3 : Wf3) + (size_t)ek * 768 + oo * 96 + c * 3 + di;
            else if (grp == 2) W = (fg ? Wg5 : Wf5) + (size_t)ek * 1280 + oo * 160 + c * 5 + di;
            else W = (fg ? Wg7 : Wf7) + (size_t)ek * 1792 + oo * 224 + c * 7 + di;
            val = *W;
        }
        Wb_k[idx] = f2bf(val);
    } else if (bx < 114) {
        int e = bx - 112;
        int ek = e * NBK + kb;
        const float* W1 = Wgc1 + (size_t)ek * 32 * 96;
        const float* W2 = Wgc2 + (size_t)ek * 32 * 96;
        for (int idx = threadIdx.x; idx < 32 * 160; idx += 256) {
            int co = idx / 160, k = idx % 160;
            int slot = k >> 5, cp = k & 31;
            float val;
            if (slot == 0)
                val = W1[co * 96 + cp] + W1[co * 96 + 32 + cp] + W1[co * 96 + 64 + cp] +
                      W2[co * 96 + cp] + W2[co * 96 + 32 + cp] + W2[co * 96 + 64 + cp];
            else if (slot == 1) val = 0.5f * W1[co * 96 + 32 + cp] + W1[co * 96 + 64 + cp];
            else if (slot == 2) val = 0.25f * W1[co * 96 + 64 + cp];
            else if (slot == 3) val = 0.5f * W2[co * 96 + 32 + cp] + W2[co * 96 + 64 + cp];
            else val = 0.25f * W2[co * 96 + 64 + cp];
            Amix_k[((size_t)e * 32 + co) * 160 + k] = f2bf(val);
        }
        if (threadIdx.x < 32)
            bsum_k[e * 32 + threadIdx.x] =
                bgc1[ek * 32 + threadIdx.x] + bgc2[ek * 32 + threadIdx.x];
    } else {
        int e = bx - 114;
        int ek = e * NBK + kb;
        ushort_t* Wh = Whd_k + (size_t)e * 6144;
        for (int i = threadIdx.x; i < 2048; i += 256)
            Wh[i] = f2bf(Wb1[(size_t)ek * 2048 + i]);
        for (int i = threadIdx.x; i < 1024; i += 256) {
            int r = i >> 6, d = i & 63;
            Wh[2048 + i] = f2bf(r < 12 ? Wb2[(size_t)ek * 768 + r * 64 + d] : 0.f);
        }
        for (int i = threadIdx.x; i < 2048; i += 256)
            Wh[3072 + i] = f2bf(Wfc1[(size_t)ek * 2048 + i]);
        for (int i = threadIdx.x; i < 1024; i += 256) {
            int r = i >> 6, d = i & 63;
            Wh[5120 + i] = f2bf(r < 12 ? Wfc2[(size_t)ek * 768 + r * 64 + d] : 0.f);
        }
        if (threadIdx.x < 64) {
            int d = threadIdx.x;
            float s1 = 0.f, s2 = 0.f;
            for (int c = 0; c < 32; ++c) {
                s1 += Wb1[(size_t)ek * 2048 + d * 32 + c];
                s2 += Wfc1[(size_t)ek * 2048 + d * 32 + c];
            }
            rS_k[e * 128 + d] = s1;
            rS_k[e * 128 + 64 + d] = s2;
        }
    }
}

// ---------------------------------------------------------------------------
// start: writes ONLY bf16 state xb [eb][t][n][c]
__global__ __launch_bounds__(256) void k_start(const float* __restrict__ bkc,
                                               ushort_t* __restrict__ xb,
                                               const float* __restrict__ Wst,
                                               const float* __restrict__ bst,
                                               int kb) {
    int n = blockIdx.x * 256 + threadIdx.x;
    int t = blockIdx.y;
    int eb = blockIdx.z;
    int e = eb >> 3;
    int ek = e * NBK + kb;
    const float* Wp = Wst + (size_t)ek * 32 * 2;
    const float* bp = bst + (size_t)ek * 32;
    float in0 = 0.f, in1 = 0.f;
    if (t >= 14) {
        const float* p = bkc + ((size_t)(eb * 12 + (t - 14)) * 512 + n) * 2;
        in0 = p[0];
        in1 = p[1];
    }
    ushort_t tmp[32];
#pragma unroll
    for (int c = 0; c < 32; ++c)
        tmp[c] = f2bf(bp[c] + Wp[c * 2] * in0 + Wp[c * 2 + 1] * in1);
    ushort_t* xbp = xb + ((size_t)(eb * 26 + t) * 512 + n) * 32;
#pragma unroll
    for (int q = 0; q < 4; ++q)
        *(bf16x8*)(xbp + q * 8) = *(bf16x8*)(tmp + q * 8);
}

// ---------------------------------------------------------------------------
// MFMA inception: writes h_old [col][n] (GEMM A operand) + buf5 slot0 (Y)
__global__ __launch_bounds__(256) void k_incept_mfma(
    const ushort_t* __restrict__ xb, ushort_t* __restrict__ h,
    ushort_t* __restrict__ buf5, const ushort_t* __restrict__ Wb,
    const float* __restrict__ bf, const float* __restrict__ bg,
    int kb, int cur_len, int L) {
    int j = blockIdx.y, eb = blockIdx.z, e = eb >> 3, ek = e * NBK + kb;
    int tid = threadIdx.x;
    int w = tid >> 6, lane = tid & 63;
    int l15 = lane & 15, lg = lane >> 4;
    int ot = w >> 1;
    int n0base = blockIdx.x * 128 + (w & 1) * 64;
    int t0 = 26 - cur_len + j;

    const ushort_t* WbE = Wb + (size_t)e * 14336;
    bf16x8 af_[7], ag_[7];
#pragma unroll
    for (int dt = 0; dt < 7; ++dt) {
        af_[dt] = *(const bf16x8*)(WbE + ((size_t)(dt * 2 + ot) * 16 + l15) * 32 + lg * 8);
        ag_[dt] = *(const bf16x8*)(WbE + 7168 + ((size_t)(dt * 2 + ot) * 16 + l15) * 32 + lg * 8);
    }
    float bfv[4], bgv[4];
#pragma unroll
    for (int r = 0; r < 4; ++r) {
        int o = ot * 16 + 4 * lg + r;
        bfv[r] = bf[ek * 32 + o];
        bgv[r] = bg[ek * 32 + o];
    }
    size_t colbase = ((size_t)eb * L + j) * 32;
    size_t rowb = ((size_t)eb * L + j) * 512;
    const ushort_t* xe = xb + ((size_t)eb * 26) * 512 * 32;
#pragma unroll
    for (int nt = 0; nt < 4; ++nt) {
        int n0 = n0base + nt * 16;
        bf16x8 bfr[7];
#pragma unroll
        for (int dt = 0; dt < 7; ++dt)
            bfr[dt] = *(const bf16x8*)(xe + ((size_t)(t0 + dt) * 512 + n0 + l15) * 32 + lg * 8);
        f32x4 accf = {}, accg = {};
#pragma unroll
        for (int dt = 0; dt < 7; ++dt) {
            accf = __builtin_amdgcn_mfma_f32_16x16x32_bf16(af_[dt], bfr[dt], accf, 0, 0, 0);
            accg = __builtin_amdgcn_mfma_f32_16x16x32_bf16(ag_[dt], bfr[dt], accg, 0, 0, 0);
        }
        u16x4 q;
#pragma unroll
        for (int r = 0; r < 4; ++r) {
            float a = accf[r] + bfv[r];
            float b = accg[r] + bgv[r];
            float hv = tanhf(a) * (1.f / (1.f + expf(-b)));
            ushort_t hb = f2bf(hv);
            q[r] = hb;
            int o = ot * 16 + 4 * lg + r;
            h[(colbase + o) * 512 + n0 + l15] = hb;
        }
        *(u16x4*)(buf5 + (rowb + n0 + l15) * 160 + ot * 16 + 4 * lg) = q;
    }
}

// ---------------------------------------------------------------------------
// 4-way NT GEMM from h with LDS-staged B tile (r12-verified shape, BK=32).
// slot z+1 of buf5 = h @ Bz^T; z: 0->An, 1->An2, 2->AnT, 3->An2T
__global__ __launch_bounds__(256) void k_gemm4(
    const ushort_t* __restrict__ A,
    const ushort_t* __restrict__ B0, const ushort_t* __restrict__ B1,
    const ushort_t* __restrict__ B2, const ushort_t* __restrict__ B3,
    ushort_t* __restrict__ buf5) {
    __shared__ __align__(16) ushort_t Bs[2][64][36];
    int z = blockIdx.z;
    const ushort_t* B = (z == 0) ? B0 : (z == 1) ? B1 : (z == 2) ? B2 : B3;
    int slot = z + 1;
    int tid = threadIdx.x;
    int w = tid >> 6, lane = tid & 63;
    int l15 = lane & 15, lg = lane >> 4;
    int wbase = blockIdx.x * 256 + w * 64;
    int n0 = blockIdx.y * 64;
    int scol = tid >> 2;          // 0..63
    int skq = (tid & 3) * 8;      // 0,8,16,24
    const ushort_t* Bsrc = B + (size_t)(n0 + scol) * 512 + skq;
    const ushort_t* Ap = A + (size_t)(wbase + l15) * 512 + lg * 8;
    f32x4 acc[4][4] = {};
    bf16x8 bregN;
    {
        bf16x8 b0r = *(const bf16x8*)(Bsrc);
        bregN = *(const bf16x8*)(Bsrc + 32);
        *(bf16x8*)&Bs[0][scol][skq] = b0r;
    }
    __syncthreads();
#pragma unroll 2
    for (int ks = 0; ks < 16; ++ks) {
        int cur = ks & 1;
        int k0 = ks * 32;
        bf16x8 av[4], bv[4];
#pragma unroll
        for (int mf = 0; mf < 4; ++mf)
            av[mf] = *(const bf16x8*)(Ap + (size_t)mf * 16 * 512 + k0);
#pragma unroll
        for (int nf = 0; nf < 4; ++nf)
            bv[nf] = *(const bf16x8*)&Bs[cur][16 * nf + l15][lg * 8];
        if (ks < 15) *(bf16x8*)&Bs[cur ^ 1][scol][skq] = bregN;   // chunk ks+1
        if (ks < 14) bregN = *(const bf16x8*)(Bsrc + (ks + 2) * 32);  // chunk ks+2
#pragma unroll
        for (int mf = 0; mf < 4; ++mf)
#pragma unroll
            for (int nf = 0; nf < 4; ++nf)
                acc[mf][nf] = __builtin_amdgcn_mfma_f32_16x16x32_bf16(
                    av[mf], bv[nf], acc[mf][nf], 0, 0, 0);
        __syncthreads();
    }
#pragma unroll
    for (int mf = 0; mf < 4; ++mf) {
        int jeb = (wbase >> 5) + (mf >> 1);
        int c0 = 16 * (mf & 1) + 4 * lg;
#pragma unroll
        for (int nf = 0; nf < 4; ++nf) {
            int col = n0 + 16 * nf + l15;
            u16x4 q;
#pragma unroll
            for (int r = 0; r < 4; ++r) q[r] = f2bf(acc[mf][nf][r]);
            *(u16x4*)(buf5 + ((size_t)jeb * 512 + col) * 160 + slot * 32 + c0) = q;
        }
    }
}

// ---------------------------------------------------------------------------
// MFMA combine: g = Amix @ buf5^T + bsum; bf16 RMW on xb state.
__global__ __launch_bounds__(256) void k_combine_mfma(
    ushort_t* __restrict__ xb,
    const ushort_t* __restrict__ buf5, const ushort_t* __restrict__ Amix,
    const float* __restrict__ bsum, int L) {
    int j = blockIdx.x, eb = blockIdx.y, e = eb >> 3;
    int tid = threadIdx.x, wv = tid >> 6, lane = tid & 63;
    int l15 = lane & 15, lg = lane >> 4;
    int t = 26 - L + j;
    const ushort_t* Ae = Amix + (size_t)e * 32 * 160;
    bf16x8 a[2][5];
#pragma unroll
    for (int ct = 0; ct < 2; ++ct)
#pragma unroll
        for (int ks = 0; ks < 5; ++ks)
            a[ct][ks] = *(const bf16x8*)(Ae + (size_t)(ct * 16 + l15) * 160 + ks * 32 + lg * 8);
    float bs[2][4];
#pragma unroll
    for (int ct = 0; ct < 2; ++ct)
#pragma unroll
        for (int r = 0; r < 4; ++r) bs[ct][r] = bsum[e * 32 + ct * 16 + 4 * lg + r];
    size_t rowb = ((size_t)eb * L + j) * 512;
    ushort_t* xbt = xb + ((size_t)(eb * 26 + t) * 512) * 32;
#pragma unroll
    for (int nt = 0; nt < 8; ++nt) {
        int n = wv * 128 + nt * 16 + l15;
        const ushort_t* bp = buf5 + (rowb + n) * 160 + lg * 8;
        bf16x8 b[5];
#pragma unroll
        for (int ks = 0; ks < 5; ++ks) b[ks] = *(const bf16x8*)(bp + ks * 32);
        f32x4 acc[2] = {};
#pragma unroll
        for (int ks = 0; ks < 5; ++ks) {
            acc[0] = __builtin_amdgcn_mfma_f32_16x16x32_bf16(a[0][ks], b[ks], acc[0], 0, 0, 0);
            acc[1] = __builtin_amdgcn_mfma_f32_16x16x32_bf16(a[1][ks], b[ks], acc[1], 0, 0, 0);
        }
#pragma unroll
        for (int ct = 0; ct < 2; ++ct) {
            ushort_t* addr = xbt + (size_t)n * 32 + ct * 16 + 4 * lg;
            u16x4 old = *(u16x4*)addr;
            u16x4 q;
#pragma unroll
            for (int r = 0; r < 4; ++r) {
                float nv = bf2f(old[r]) - 0.25f * (acc[ct][r] + bs[ct][r]);
                q[r] = f2bf(nv);
            }
            *(u16x4*)addr = q;
        }
    }
}

// ---------------------------------------------------------------------------
// heads with INLINE layernorm stats (computed redundantly per block from xb;
// deterministic: identical reduction order in every block).
__global__ __launch_bounds__(256) void k_heads_mfma(
    const ushort_t* __restrict__ xb,
    float* __restrict__ bkc, float* __restrict__ acc,
    const ushort_t* __restrict__ Whd, const float* __restrict__ rS,
    const float* __restrict__ bb1, const float* __restrict__ bb2,
    const float* __restrict__ bfc1, const float* __restrict__ bfc2,
    int kb) {
    __shared__ __align__(16) ushort_t lds[4][64][72];
    __shared__ float r1[4], r2[4];
    int w = blockIdx.y, eb = blockIdx.z;
    int e = eb >> 3, ek = e * NBK + kb;
    int tid = threadIdx.x, wv = tid >> 6, lane = tid & 63;
    int l15 = lane & 15, lg = lane >> 4;
    int n0 = blockIdx.x * 256 + wv * 64;
    // ---- inline stats over xb[t=24..25] (32768 contiguous bf16) ----
    const ushort_t* sp = xb + ((size_t)(eb * 26 + 24) * 512) * 32;
    float s = 0.f, s2 = 0.f;
    for (int i = tid * 8; i < 32768; i += 256 * 8) {
        bf16x8 v8 = *(const bf16x8*)(sp + i);
#pragma unroll
        for (int q = 0; q < 8; ++q) {
            float v = bf2f((ushort_t)v8[q]);
            s += v;
            s2 += v * v;
        }
    }
    for (int off = 32; off; off >>= 1) {
        s += __shfl_down(s, off);
        s2 += __shfl_down(s2, off);
    }
    if ((tid & 63) == 0) { r1[tid >> 6] = s; r2[tid >> 6] = s2; }
    __syncthreads();
    float S = r1[0] + r1[1] + r1[2] + r1[3];
    float S2 = r2[0] + r2[1] + r2[2] + r2[3];
    float mu = S / 32768.f;
    float rsv = rsqrtf(S2 / 32768.f - mu * mu + 1e-5f);
    __syncthreads();
    // ---- heads ----
    const ushort_t* Wh = Whd + (size_t)e * 6144;
    const ushort_t* xrow = xb + ((size_t)(eb * 26 + 24 + w) * 512) * 32;

#pragma unroll
    for (int head = 0; head < 2; ++head) {
        if (head == 1 && w == 0) break;  // fc only for w==1
        int woff = head ? 3072 : 0;
        const float* b1 = head ? bfc1 : bb1;
        const float* b2 = head ? bfc2 : bb2;
        const float* rs1 = rS + e * 128 + (head ? 64 : 0);
        bf16x8 a1[4];
#pragma unroll
        for (int rt = 0; rt < 4; ++rt)
            a1[rt] = *(const bf16x8*)(Wh + woff + (size_t)(rt * 16 + l15) * 32 + lg * 8);
        float be[4][4];
#pragma unroll
        for (int rt = 0; rt < 4; ++rt)
#pragma unroll
            for (int r = 0; r < 4; ++r) {
                int d = rt * 16 + 4 * lg + r;
                be[rt][r] = b1[ek * 64 + d] - rsv * mu * rs1[d];
            }
#pragma unroll
        for (int nt = 0; nt < 4; ++nt) {
            bf16x8 bv = *(const bf16x8*)(xrow + (size_t)(n0 + nt * 16 + l15) * 32 + lg * 8);
            f32x4 ac[4] = {};
#pragma unroll
            for (int rt = 0; rt < 4; ++rt)
                ac[rt] = __builtin_amdgcn_mfma_f32_16x16x32_bf16(a1[rt], bv, ac[rt], 0, 0, 0);
#pragma unroll
            for (int rt = 0; rt < 4; ++rt)
#pragma unroll
                for (int r = 0; r < 4; ++r) {
                    float hv = fmaxf(rsv * ac[rt][r] + be[rt][r], 0.f);
                    lds[wv][nt * 16 + l15][rt * 16 + 4 * lg + r] = f2bf(hv);
                }
        }
        bf16x8 a2[2];
        a2[0] = *(const bf16x8*)(Wh + woff + 2048 + (size_t)l15 * 64 + lg * 8);
        a2[1] = *(const bf16x8*)(Wh + woff + 2048 + (size_t)l15 * 64 + 32 + lg * 8);
        float b2v[4];
#pragma unroll
        for (int r = 0; r < 4; ++r) {
            int s12 = 4 * lg + r;
            b2v[r] = (s12 < 12) ? b2[ek * 12 + s12] : 0.f;
        }
#pragma unroll
        for (int nt = 0; nt < 4; ++nt) {
            bf16x8 b0 = *(const bf16x8*)&lds[wv][nt * 16 + l15][lg * 8];
            bf16x8 b1f = *(const bf16x8*)&lds[wv][nt * 16 + l15][32 + lg * 8];
            f32x4 ac2 = {};
            ac2 = __builtin_amdgcn_mfma_f32_16x16x32_bf16(a2[0], b0, ac2, 0, 0, 0);
            ac2 = __builtin_amdgcn_mfma_f32_16x16x32_bf16(a2[1], b1f, ac2, 0, 0, 0);
#pragma unroll
            for (int r = 0; r < 4; ++r) {
                int s12 = 4 * lg + r;
                if (s12 < 12) {
                    int n = n0 + nt * 16 + l15;
                    float val = ac2[r] + b2v[r];
                    if (head == 0)
                        bkc[((size_t)(eb * 12 + s12) * 512 + n) * 2 + w] -= val;
                    else
                        acc[(size_t)(eb * 12 + s12) * 512 + n] += val;
                }
            }
        }
    }
}

// ---------------------------------------------------------------------------
__global__ __launch_bounds__(256) void k_final(const float* __restrict__ acc,
                                               const float* __restrict__ ew,
                                               float* __restrict__ out) {
    int i = blockIdx.x * 256 + threadIdx.x;  // 49152
    out[i] = ew[0] * acc[i] + ew[1] * acc[49152 + i];
}

// ---------------------------------------------------------------------------
extern "C" void kernel_launch(void* const* d_in, const int* in_sizes, int n_in,
                              void* d_out, int out_size, void* d_ws, size_t ws_size,
                              hipStream_t stream) {
    const float* X    = (const float*)d_in[0];
    const float* adj  = (const float*)d_in[1];
    const float* ew   = (const float*)d_in[2];
    const float* Wst  = (const float*)d_in[3];
    const float* bst  = (const float*)d_in[4];
    const float* Wf2  = (const float*)d_in[5];
    const float* Wf3  = (const float*)d_in[6];
    const float* Wf5  = (const float*)d_in[7];
    const float* Wf7  = (const float*)d_in[8];
    const float* bf   = (const float*)d_in[9];
    const float* Wg2  = (const float*)d_in[10];
    const float* Wg3  = (const float*)d_in[11];
    const float* Wg5  = (const float*)d_in[12];
    const float* Wg7  = (const float*)d_in[13];
    const float* bg   = (const float*)d_in[14];
    const float* Wgc1 = (const float*)d_in[15];
    const float* bgc1 = (const float*)d_in[16];
    const float* Wgc2 = (const float*)d_in[17];
    const float* bgc2 = (const float*)d_in[18];
    const float* Wb1  = (const float*)d_in[19];
    const float* bb1  = (const float*)d_in[20];
    const float* Wb2  = (const float*)d_in[21];
    const float* bb2  = (const float*)d_in[22];
    const float* Wfc1 = (const float*)d_in[23];
    const float* bfc1 = (const float*)d_in[24];
    const float* Wfc2 = (const float*)d_in[25];
    const float* bfc2 = (const float*)d_in[26];

    float* ws = (float*)d_ws;
    size_t off = 0;
    auto alloc = [&](size_t nf) { float* p = ws + off; off += nf; return p; };
    float* di    = alloc(512);
    ushort_t* Anb   = (ushort_t*)alloc(512 * 512 / 2);
    ushort_t* AnTb  = (ushort_t*)alloc(512 * 512 / 2);
    ushort_t* An2b  = (ushort_t*)alloc(512 * 512 / 2);
    ushort_t* An2Tb = (ushort_t*)alloc(512 * 512 / 2);
    float* bkc   = alloc((size_t)EE * BATCH * 12 * 512 * 2);
    float* acc   = alloc((size_t)EE * BATCH * 12 * 512);
    ushort_t* Amix = (ushort_t*)alloc(2 * 10240 / 2);     // [kb][e][32][160]
    float* bsum  = alloc(128);                             // [kb][e][32]
    ushort_t* Wb = (ushort_t*)alloc(2 * 28672 / 2);        // [kb][...]
    ushort_t* Whd = (ushort_t*)alloc(2 * 12288 / 2);       // [kb][...]
    float* rSb   = alloc(512);                             // [kb][e][2][64]
    ushort_t* xb = (ushort_t*)alloc((size_t)16 * 26 * 512 * 32 / 2);
    size_t hbuf_f = (size_t)16 * 20 * 32 * 512 / 2;
    ushort_t* h   = (ushort_t*)alloc(hbuf_f);
    ushort_t* buf5 = (ushort_t*)alloc((size_t)16 * 20 * 512 * 160 / 2);
    if (off * sizeof(float) > ws_size) return;  // workspace too small: bail

    // Graph normalization + An^2 precompute + all weight prep (both kb)
    k_rowsum<<<512, 256, 0, stream>>>(adj, di);
    k_norm<<<1024, 256, 0, stream>>>(adj, di, Anb, AnTb);
    k_An2<<<dim3(2, 8), 256, 0, stream>>>(Anb, AnTb, An2b, An2Tb);
    k_prep<<<232, 256, 0, stream>>>(Wf2, Wf3, Wf5, Wf7, Wg2, Wg3, Wg5, Wg7, Wb,
                                    Wgc1, bgc1, Wgc2, bgc2, Amix, bsum,
                                    Wb1, Wb2, Wfc1, Wfc2, Whd, rSb);

    // Residual init (both experts start from X) + output accumulator zero
    hipMemcpyAsync(bkc, X, (size_t)98304 * 4, hipMemcpyDeviceToDevice, stream);
    hipMemcpyAsync(bkc + 98304, X, (size_t)98304 * 4, hipMemcpyDeviceToDevice, stream);
    hipMemsetAsync(acc, 0, (size_t)EE * BATCH * 12 * 512 * 4, stream);

    for (int kb = 0; kb < NBK; ++kb) {
        k_start<<<dim3(2, 26, 16), 256, 0, stream>>>(bkc, xb, Wst, bst, kb);
        int cur = 26;
        for (int it = 0; it < 4; ++it) {
            int L = cur - 6;
            k_incept_mfma<<<dim3(4, L, 16), 256, 0, stream>>>(
                xb, h, buf5, Wb + (size_t)kb * 28672, bf, bg, kb, cur, L);
            k_gemm4<<<dim3(2 * L, 8, 4), 256, 0, stream>>>(
                h, Anb, An2b, AnTb, An2Tb, buf5);
            k_combine_mfma<<<dim3(L, 16), 256, 0, stream>>>(
                xb, buf5, Amix + (size_t)kb * 10240, bsum + kb * 64, L);
            cur -= 6;
        }
        k_heads_mfma<<<dim3(2, 2, 16), 256, 0, stream>>>(
            xb, bkc, acc, Whd + (size_t)kb * 12288, rSb + kb * 256,
            bb1, bb2, bfc1, bfc2, kb);
    }
    k_final<<<192, 256, 0, stream>>>(acc, ew, (float*)d_out);
}